// Round 4
// baseline (776.766 us; speedup 1.0000x reference)
//
#include <hip/hip_runtime.h>

// GCN forward: 3x GCNConv (symmetric norm, self-loops) + mean-pool + MLP head.
// R4: bucketed two-pass CSR build (radix partition) to kill the 15x write
//     amplification seen in the single-pass random scatter.

constexpr int NPB_SH = 5;    // 32 nodes per bucket
constexpr int SUB    = 8;    // sub-streams per bucket (~XCD-private via blockIdx&7)
constexpr int CAP    = 256;  // slots per (bucket,sub); mean fill ~128, fixed input
constexpr int EPB    = 4096; // edges per pass-1 block (256 thr x 16)

__global__ void k_fill_f(float* __restrict__ p, float v, int n) {
    int i = blockIdx.x * blockDim.x + threadIdx.x;
    if (i < n) p[i] = v;
}

__global__ void k_fill_i(int* __restrict__ p, int v, int n) {
    int i = blockIdx.x * blockDim.x + threadIdx.x;
    if (i < n) p[i] = v;
}

__global__ void k_init_pcur(int* __restrict__ pcur, int m) {
    int j = blockIdx.x * blockDim.x + threadIdx.x;
    if (j < m) pcur[j] = j * CAP;
}

// Pass 1: degree histogram + bucket partition (packed 4B entries).
__global__ void k_part(const int* __restrict__ src, const int* __restrict__ dst,
                       int* __restrict__ ideg, int* __restrict__ pcur,
                       unsigned* __restrict__ ebuf, int nE) {
    int sub = blockIdx.x & (SUB - 1);
    int base = blockIdx.x * EPB;
    for (int it = 0; it < EPB / 256; ++it) {
        int e = base + it * 256 + threadIdx.x;
        if (e < nE) {
            int s = src[e], d = dst[e];
            atomicAdd(&ideg[d], 1);
            int pos = atomicAdd(&pcur[((d >> NPB_SH) << 3) + sub], 1);
            ebuf[pos] = ((unsigned)(d & ((1 << NPB_SH) - 1)) << 17) | (unsigned)s;
        }
    }
}

// Ordered exclusive scan of bucket totals -> bucket cursors (1 block, 256 thr).
__global__ void k_bscan(const int* __restrict__ pcur, int* __restrict__ bcursor, int NB) {
    __shared__ int part[256];
    int t = threadIdx.x;
    int chunk = (NB + 255) / 256;
    int lo = t * chunk, hi = min(lo + chunk, NB);
    int sum = 0;
    for (int b = lo; b < hi; ++b) {
        int tot = 0;
        #pragma unroll
        for (int s = 0; s < SUB; ++s) tot += pcur[b * 8 + s] - (b * 8 + s) * CAP;
        sum += tot;
    }
    part[t] = sum;
    __syncthreads();
    for (int off = 1; off < 256; off <<= 1) {
        int v = (t >= off) ? part[t - off] : 0;
        __syncthreads();
        part[t] += v;
        __syncthreads();
    }
    int run = (t == 0) ? 0 : part[t - 1];
    for (int b = lo; b < hi; ++b) {
        int tot = 0;
        #pragma unroll
        for (int s = 0; s < SUB; ++s) tot += pcur[b * 8 + s] - (b * 8 + s) * CAP;
        bcursor[b] = run;
        run += tot;
    }
}

// dinv = rsqrt(deg+1); node slab allocated inside its bucket's region.
__global__ void k_alloc(const int* __restrict__ ideg, float* __restrict__ dinv,
                        int* __restrict__ start, int* __restrict__ cursor,
                        int* __restrict__ bcursor, int n) {
    int i = blockIdx.x * blockDim.x + threadIdx.x;
    if (i < n) {
        int dg = ideg[i];
        dinv[i] = rsqrtf((float)(dg + 1));
        int st = atomicAdd(&bcursor[i >> NPB_SH], dg);
        start[i] = st;
        cursor[i] = st;
    }
}

// Pass 2: one block per bucket; scatter col within a ~4KB L2-resident window.
__global__ void k_fill2(const int* __restrict__ pcur, const unsigned* __restrict__ ebuf,
                        int* __restrict__ cursor, int* __restrict__ col) {
    int b = blockIdx.x;
    for (int s = 0; s < SUB; ++s) {
        int idx8 = b * 8 + s;
        int base = idx8 * CAP;
        int cnt = pcur[idx8] - base;
        for (int t = threadIdx.x; t < cnt; t += 256) {
            unsigned v = ebuf[base + t];
            int d = (b << NPB_SH) + (int)(v >> 17);
            int pos = atomicAdd(&cursor[d], 1);
            col[pos] = (int)(v & 0x1FFFFu);
        }
    }
}

// Aggregation over dinv-prescaled rows T:
//   EPI 0: out = dinv[i]*total ; EPI 1: out = dinv[i]*relu(dinv[i]*total + b)
template <int F, int EPI>
__global__ void k_agg(const float* __restrict__ T, const int* __restrict__ start,
                      const int* __restrict__ cnt, const int* __restrict__ col,
                      const float* __restrict__ dinv, const float* __restrict__ bias,
                      float* __restrict__ out, int n) {
    constexpr int TPN = F / 4;
    int idx = blockIdx.x * blockDim.x + threadIdx.x;
    int i = idx / TPN;
    int q = idx % TPN;
    if (i >= n) return;
    const float4* T4 = (const float4*)T;
    int base = start[i], c = cnt[i];
    float4 acc = T4[(size_t)i * TPN + q];  // self term
    int k = 0;
    for (; k + 4 <= c; k += 4) {
        int s0 = col[base + k],     s1 = col[base + k + 1];
        int s2 = col[base + k + 2], s3 = col[base + k + 3];
        float4 v0 = T4[(size_t)s0 * TPN + q];
        float4 v1 = T4[(size_t)s1 * TPN + q];
        float4 v2 = T4[(size_t)s2 * TPN + q];
        float4 v3 = T4[(size_t)s3 * TPN + q];
        acc.x += v0.x + v1.x + v2.x + v3.x;
        acc.y += v0.y + v1.y + v2.y + v3.y;
        acc.z += v0.z + v1.z + v2.z + v3.z;
        acc.w += v0.w + v1.w + v2.w + v3.w;
    }
    for (; k < c; ++k) {
        float4 v = T4[(size_t)col[base + k] * TPN + q];
        acc.x += v.x; acc.y += v.y; acc.z += v.z; acc.w += v.w;
    }
    float d = dinv[i];
    float4 o;
    if (EPI == 0) {
        o.x = d * acc.x; o.y = d * acc.y; o.z = d * acc.z; o.w = d * acc.w;
    } else {
        float4 b = ((const float4*)bias)[q];
        o.x = d * fmaxf(d * acc.x + b.x, 0.0f);
        o.y = d * fmaxf(d * acc.y + b.y, 0.0f);
        o.z = d * fmaxf(d * acc.z + b.z, 0.0f);
        o.w = d * fmaxf(d * acc.w + b.w, 0.0f);
    }
    ((float4*)out)[(size_t)i * TPN + q] = o;
}

// out[i][f] = epilogue( sum_k H[i][k]*W[k][f] )
//   EPI 0: dinv*mm ; EPI 1: dinv*relu(mm+b) ; EPI 2: relu(mm+b)
template <int K, int F, int EPI>
__global__ void k_mm(const float* __restrict__ H, const float* __restrict__ W,
                     const float* __restrict__ b, const float* __restrict__ dinv,
                     float* __restrict__ out, int n) {
    __shared__ float sW[K * F];
    for (int t = threadIdx.x; t < K * F; t += blockDim.x) sW[t] = W[t];
    __syncthreads();
    int idx = blockIdx.x * blockDim.x + threadIdx.x;
    int i = idx / F, f = idx % F;
    if (i >= n) return;
    const float* h = H + (size_t)i * K;
    float acc = (EPI == 0) ? 0.0f : b[f];
    #pragma unroll 8
    for (int k = 0; k < K; ++k) acc += h[k] * sW[k * F + f];
    if (EPI != 0) acc = fmaxf(acc, 0.0f);
    if (EPI != 2) acc *= dinv[i];
    out[(size_t)i * F + f] = acc;
}

// batch is sorted: run-length accumulate, one atomic per (graph-run, feature).
__global__ void k_pool(const float* __restrict__ h3, const int* __restrict__ batch,
                       float* __restrict__ pooled, float* __restrict__ gcnt, int n) {
    const int CHUNK = 128;
    int cs = blockIdx.x * CHUNK;
    int ce = min(cs + CHUNK, n);
    int f = threadIdx.x & 63;
    int r = threadIdx.x >> 6;
    int cur = -1;
    float acc = 0.0f, cn = 0.0f;
    for (int i = cs + r; i < ce; i += 4) {
        int g = batch[i];
        if (g != cur) {
            if (cur >= 0) {
                atomicAdd(&pooled[cur * 64 + f], acc);
                if (f == 0) atomicAdd(&gcnt[cur], cn);
            }
            cur = g; acc = 0.0f; cn = 0.0f;
        }
        acc += h3[(size_t)i * 64 + f];
        cn += 1.0f;
    }
    if (cur >= 0) {
        atomicAdd(&pooled[cur * 64 + f], acc);
        if (f == 0) atomicAdd(&gcnt[cur], cn);
    }
}

// one block (64 threads) per graph: mean -> relu(mean@Wl1+bl1) -> @Wl2+bl2
__global__ void k_head(const float* __restrict__ pooled, const float* __restrict__ gcnt,
                       const float* __restrict__ Wl1, const float* __restrict__ bl1,
                       const float* __restrict__ Wl2, const float* __restrict__ bl2,
                       float* __restrict__ out) {
    int g = blockIdx.x;
    int t = threadIdx.x;
    __shared__ float mean[64];
    __shared__ float hid[64];
    float c = fmaxf(gcnt[g], 1.0f);
    mean[t] = pooled[g * 64 + t] / c;
    __syncthreads();
    float acc = bl1[t];
    #pragma unroll 8
    for (int k = 0; k < 64; ++k) acc += mean[k] * Wl1[k * 64 + t];
    hid[t] = fmaxf(acc, 0.0f);
    __syncthreads();
    if (t < 2) {
        float o = bl2[t];
        #pragma unroll 8
        for (int k = 0; k < 64; ++k) o += hid[k] * Wl2[k * 2 + t];
        out[g * 2 + t] = o;
    }
}

extern "C" void kernel_launch(void* const* d_in, const int* in_sizes, int n_in,
                              void* d_out, int out_size, void* d_ws, size_t ws_size,
                              hipStream_t stream) {
    const float* x    = (const float*)d_in[0];
    const int*   ei   = (const int*)d_in[1];
    const int*   batch= (const int*)d_in[2];
    const float* W1   = (const float*)d_in[3];
    const float* b1   = (const float*)d_in[4];
    const float* W2   = (const float*)d_in[5];
    const float* b2   = (const float*)d_in[6];
    const float* W3   = (const float*)d_in[7];
    const float* b3   = (const float*)d_in[8];
    const float* Wl1  = (const float*)d_in[9];
    const float* bl1  = (const float*)d_in[10];
    const float* Wl2  = (const float*)d_in[11];
    const float* bl2  = (const float*)d_in[12];
    float* out = (float*)d_out;

    const int n  = in_sizes[2];      // 100000
    const int nE = in_sizes[1] / 2;  // 3200000
    const int* src = ei;
    const int* dst = ei + nE;

    const int NB = (n + (1 << NPB_SH) - 1) >> NPB_SH;  // 3125 buckets
    const int NPC = NB * SUB;                          // 25000 sub-cursors

    char* w = (char*)d_ws;
    auto alloc_f = [&](size_t cnt) { float* p = (float*)w; w += cnt * 4; return p; };
    auto alloc_i = [&](size_t cnt) { int*   p = (int*)w;   w += cnt * 4; return p; };

    float*    dinv    = alloc_f(n);
    int*      ideg    = alloc_i(n);
    int*      start   = alloc_i(n);
    int*      cursor  = alloc_i(n);
    int*      pcur    = alloc_i(NPC);
    int*      bcursor = alloc_i(NB);
    unsigned* ebuf    = (unsigned*)alloc_i((size_t)NPC * CAP);  // 25.6 MB
    int*      col     = alloc_i(nE);
    // feature region (Pd1,h1d dead before agg3; everything dead before mm3)
    float* Pd1    = alloc_f((size_t)n * 16);
    float* h1d    = alloc_f((size_t)n * 16);
    float* a1     = alloc_f((size_t)n * 16);
    float* h2d    = alloc_f((size_t)n * 32);
    float* a2     = Pd1;             // 32n floats over Pd1+h1d (both dead)
    float* h3     = (float*)ebuf;    // 64n floats; ebuf dead after pass 2
    float* pooled = alloc_f(1024 * 64);
    float* gcnt   = alloc_f(1024);

    const int B = 256;
    auto g = [&](long long t) { return (int)((t + B - 1) / B); };

    // ---- CSR build: histogram+partition -> bucket scan -> alloc -> bucket fill
    k_fill_i<<<g(n), B, 0, stream>>>(ideg, 0, n);
    k_init_pcur<<<g(NPC), B, 0, stream>>>(pcur, NPC);
    k_part<<<(nE + EPB - 1) / EPB, B, 0, stream>>>(src, dst, ideg, pcur, ebuf, nE);
    k_bscan<<<1, 256, 0, stream>>>(pcur, bcursor, NB);
    k_alloc<<<g(n), B, 0, stream>>>(ideg, dinv, start, cursor, bcursor, n);
    k_fill2<<<NB, B, 0, stream>>>(pcur, ebuf, cursor, col);

    // ---- layer 1: Pd1 = dinv*(x@W1); h1d = dinv*relu(dinv*Agg(Pd1)+b1)
    k_mm<128, 16, 0><<<g((long long)n * 16), B, 0, stream>>>(x, W1, nullptr, dinv, Pd1, n);
    k_agg<16, 1><<<g((long long)n * 4), B, 0, stream>>>(Pd1, start, ideg, col, dinv, b1, h1d, n);

    // ---- layer 2: a1 = dinv*Agg(h1d); h2d = dinv*relu(a1@W2+b2)
    k_agg<16, 0><<<g((long long)n * 4), B, 0, stream>>>(h1d, start, ideg, col, dinv, nullptr, a1, n);
    k_mm<16, 32, 1><<<g((long long)n * 32), B, 0, stream>>>(a1, W2, b2, dinv, h2d, n);

    // ---- layer 3: a2 = dinv*Agg(h2d); h3 = relu(a2@W3+b3)
    k_agg<32, 0><<<g((long long)n * 8), B, 0, stream>>>(h2d, start, ideg, col, dinv, nullptr, a2, n);
    k_mm<32, 64, 2><<<g((long long)n * 64), B, 0, stream>>>(a2, W3, b3, dinv, h3, n);

    // ---- global mean pool + MLP head
    k_fill_f<<<g(1024 * 64 + 1024), B, 0, stream>>>(pooled, 0.0f, 1024 * 64 + 1024);
    k_pool<<<(n + 127) / 128, B, 0, stream>>>(h3, batch, pooled, gcnt, n);
    k_head<<<1024, 64, 0, stream>>>(pooled, gcnt, Wl1, bl1, Wl2, bl2, out);
}

// Round 5
// 423.740 us; speedup vs baseline: 1.8331x; 1.8331x over previous
//
#include <hip/hip_runtime.h>

// GCN forward: 3x GCNConv (symmetric norm, self-loops) + mean-pool + MLP head.
// R5: zero-global-atomic CSR build (two-level counting sort, LDS cursors only)
//     + atomic-free fused pool/head (sorted batch -> binary-searched bounds).
// Lesson from R1-R4 counters: device-scope atomicAdd = ~64B HBM RMW each,
// ~770 GB/s ceiling -> per-edge global atomics are the whole cost.

constexpr int EPA    = 8192;  // edges per pass-A block
constexpr int MAXBKT = 512;   // LDS padding (NBKT = 391, NBLKA = 391)

// ---- pass A phase 1: per-block bucket histogram (LDS atomics only)
__global__ void k_histA(const int* __restrict__ dst, int* __restrict__ cnt,
                        int nE, int NBKT, int NBLKA) {
    __shared__ int hist[MAXBKT];
    for (int t = threadIdx.x; t < NBKT; t += blockDim.x) hist[t] = 0;
    __syncthreads();
    int base = blockIdx.x * EPA;
    int end = min(base + EPA, nE);
    for (int e = base + threadIdx.x; e < end; e += blockDim.x)
        atomicAdd(&hist[dst[e] >> 8], 1);
    __syncthreads();
    for (int t = threadIdx.x; t < NBKT; t += blockDim.x)
        cnt[t * NBLKA + blockIdx.x] = hist[t];  // [bucket][block], coalesced read later
}

// ---- pass A phase 2a: per-bucket exclusive scan over blocks
__global__ void k_scanA(const int* __restrict__ cnt, int* __restrict__ po,
                        int* __restrict__ totals, int NBLKA) {
    __shared__ int sc[MAXBKT];
    int j = blockIdx.x, t = threadIdx.x;  // blockDim = MAXBKT
    int v = (t < NBLKA) ? cnt[j * NBLKA + t] : 0;
    sc[t] = v;
    __syncthreads();
    for (int off = 1; off < MAXBKT; off <<= 1) {
        int u = (t >= off) ? sc[t - off] : 0;
        __syncthreads();
        sc[t] += u;
        __syncthreads();
    }
    if (t < NBLKA) po[j * NBLKA + t] = sc[t] - v;  // exclusive prefix
    if (t == MAXBKT - 1) totals[j] = sc[t];
}

// ---- pass A phase 2b: exclusive scan of bucket totals
__global__ void k_scanB(const int* __restrict__ totals, int* __restrict__ bstart,
                        int NBKT, int nE) {
    __shared__ int sc[MAXBKT];
    int t = threadIdx.x;
    int v = (t < NBKT) ? totals[t] : 0;
    sc[t] = v;
    __syncthreads();
    for (int off = 1; off < MAXBKT; off <<= 1) {
        int u = (t >= off) ? sc[t - off] : 0;
        __syncthreads();
        sc[t] += u;
        __syncthreads();
    }
    if (t < NBKT) bstart[t] = sc[t] - v;
    if (t == 0) bstart[NBKT] = nE;
}

// ---- pass A phase 3: scatter packed entries into disjoint per-(block,bucket)
//      ranges; LDS cursors, plain cached writes.
__global__ void k_scatA(const int* __restrict__ src, const int* __restrict__ dst,
                        const int* __restrict__ po, const int* __restrict__ bstart,
                        unsigned* __restrict__ ebuf, int nE, int NBKT, int NBLKA) {
    __shared__ int cur[MAXBKT];
    for (int t = threadIdx.x; t < NBKT; t += blockDim.x)
        cur[t] = po[t * NBLKA + blockIdx.x] + bstart[t];
    __syncthreads();
    int base = blockIdx.x * EPA;
    int end = min(base + EPA, nE);
    for (int e = base + threadIdx.x; e < end; e += blockDim.x) {
        int s = src[e], d = dst[e];
        int pos = atomicAdd(&cur[d >> 8], 1);  // LDS
        ebuf[pos] = ((unsigned)(d & 255) << 17) | (unsigned)s;
    }
}

// ---- pass B: per-bucket counting sort by node; writes ideg/start/dinv/col.
__global__ void k_bsort(const unsigned* __restrict__ ebuf, const int* __restrict__ bstart,
                        int* __restrict__ col, int* __restrict__ ideg,
                        int* __restrict__ start, float* __restrict__ dinv, int n) {
    __shared__ int hist[256], excl[256], cur[256];
    int b = blockIdx.x, t = threadIdx.x;
    int ebase = bstart[b], eend = bstart[b + 1];
    hist[t] = 0;
    __syncthreads();
    for (int e = ebase + t; e < eend; e += 256)
        atomicAdd(&hist[ebuf[e] >> 17], 1);  // LDS
    __syncthreads();
    int v = hist[t];
    excl[t] = v;
    __syncthreads();
    for (int off = 1; off < 256; off <<= 1) {
        int u = (t >= off) ? excl[t - off] : 0;
        __syncthreads();
        excl[t] += u;
        __syncthreads();
    }
    int ex = excl[t] - v;  // exclusive
    cur[t] = ebase + ex;
    int node = (b << 8) + t;
    if (node < n) {
        ideg[node] = v;
        start[node] = ebase + ex;
        dinv[node] = rsqrtf((float)(v + 1));
    }
    __syncthreads();
    for (int e = ebase + t; e < eend; e += 256) {
        unsigned u = ebuf[e];
        int pos = atomicAdd(&cur[u >> 17], 1);  // LDS
        col[pos] = (int)(u & 0x1FFFFu);
    }
}

// ---- aggregation over dinv-prescaled rows T:
//   EPI 0: out = dinv[i]*total ; EPI 1: out = dinv[i]*relu(dinv[i]*total + b)
template <int F, int EPI>
__global__ void k_agg(const float* __restrict__ T, const int* __restrict__ start,
                      const int* __restrict__ cnt, const int* __restrict__ col,
                      const float* __restrict__ dinv, const float* __restrict__ bias,
                      float* __restrict__ out, int n) {
    constexpr int TPN = F / 4;
    int idx = blockIdx.x * blockDim.x + threadIdx.x;
    int i = idx / TPN;
    int q = idx % TPN;
    if (i >= n) return;
    const float4* T4 = (const float4*)T;
    int base = start[i], c = cnt[i];
    float4 acc = T4[(size_t)i * TPN + q];  // self term
    int k = 0;
    for (; k + 4 <= c; k += 4) {
        int s0 = col[base + k],     s1 = col[base + k + 1];
        int s2 = col[base + k + 2], s3 = col[base + k + 3];
        float4 v0 = T4[(size_t)s0 * TPN + q];
        float4 v1 = T4[(size_t)s1 * TPN + q];
        float4 v2 = T4[(size_t)s2 * TPN + q];
        float4 v3 = T4[(size_t)s3 * TPN + q];
        acc.x += v0.x + v1.x + v2.x + v3.x;
        acc.y += v0.y + v1.y + v2.y + v3.y;
        acc.z += v0.z + v1.z + v2.z + v3.z;
        acc.w += v0.w + v1.w + v2.w + v3.w;
    }
    for (; k < c; ++k) {
        float4 v = T4[(size_t)col[base + k] * TPN + q];
        acc.x += v.x; acc.y += v.y; acc.z += v.z; acc.w += v.w;
    }
    float d = dinv[i];
    float4 o;
    if (EPI == 0) {
        o.x = d * acc.x; o.y = d * acc.y; o.z = d * acc.z; o.w = d * acc.w;
    } else {
        float4 b = ((const float4*)bias)[q];
        o.x = d * fmaxf(d * acc.x + b.x, 0.0f);
        o.y = d * fmaxf(d * acc.y + b.y, 0.0f);
        o.z = d * fmaxf(d * acc.z + b.z, 0.0f);
        o.w = d * fmaxf(d * acc.w + b.w, 0.0f);
    }
    ((float4*)out)[(size_t)i * TPN + q] = o;
}

// ---- dense per-node matmul; EPI 0: dinv*mm ; 1: dinv*relu(mm+b) ; 2: relu(mm+b)
template <int K, int F, int EPI>
__global__ void k_mm(const float* __restrict__ H, const float* __restrict__ W,
                     const float* __restrict__ b, const float* __restrict__ dinv,
                     float* __restrict__ out, int n) {
    __shared__ float sW[K * F];
    for (int t = threadIdx.x; t < K * F; t += blockDim.x) sW[t] = W[t];
    __syncthreads();
    int idx = blockIdx.x * blockDim.x + threadIdx.x;
    int i = idx / F, f = idx % F;
    if (i >= n) return;
    const float* h = H + (size_t)i * K;
    float acc = (EPI == 0) ? 0.0f : b[f];
    #pragma unroll 8
    for (int k = 0; k < K; ++k) acc += h[k] * sW[k * F + f];
    if (EPI != 0) acc = fmaxf(acc, 0.0f);
    if (EPI != 2) acc *= dinv[i];
    out[(size_t)i * F + f] = acc;
}

// ---- graph boundaries via binary search in sorted batch
__global__ void k_bounds(const int* __restrict__ batch, int* __restrict__ gstart,
                         int n, int ng) {
    int g = blockIdx.x * blockDim.x + threadIdx.x;
    if (g > ng) return;
    if (g == ng) { gstart[g] = n; return; }
    int lo = 0, hi = n;
    while (lo < hi) {
        int mid = (lo + hi) >> 1;
        if (batch[mid] < g) lo = mid + 1; else hi = mid;
    }
    gstart[g] = lo;
}

// ---- fused mean-pool + MLP head: one block (64 threads) per graph
__global__ void k_poolhead(const float* __restrict__ h3, const int* __restrict__ gstart,
                           const float* __restrict__ Wl1, const float* __restrict__ bl1,
                           const float* __restrict__ Wl2, const float* __restrict__ bl2,
                           float* __restrict__ out) {
    int g = blockIdx.x, t = threadIdx.x;
    __shared__ float mean[64], hid[64];
    int s = gstart[g], e = gstart[g + 1];
    float acc = 0.0f;
    for (int i = s; i < e; ++i) acc += h3[(size_t)i * 64 + t];
    float c = fmaxf((float)(e - s), 1.0f);
    mean[t] = acc / c;
    __syncthreads();
    float a = bl1[t];
    #pragma unroll 8
    for (int k = 0; k < 64; ++k) a += mean[k] * Wl1[k * 64 + t];
    hid[t] = fmaxf(a, 0.0f);
    __syncthreads();
    if (t < 2) {
        float o = bl2[t];
        #pragma unroll 8
        for (int k = 0; k < 64; ++k) o += hid[k] * Wl2[k * 2 + t];
        out[g * 2 + t] = o;
    }
}

extern "C" void kernel_launch(void* const* d_in, const int* in_sizes, int n_in,
                              void* d_out, int out_size, void* d_ws, size_t ws_size,
                              hipStream_t stream) {
    const float* x    = (const float*)d_in[0];
    const int*   ei   = (const int*)d_in[1];
    const int*   batch= (const int*)d_in[2];
    const float* W1   = (const float*)d_in[3];
    const float* b1   = (const float*)d_in[4];
    const float* W2   = (const float*)d_in[5];
    const float* b2   = (const float*)d_in[6];
    const float* W3   = (const float*)d_in[7];
    const float* b3   = (const float*)d_in[8];
    const float* Wl1  = (const float*)d_in[9];
    const float* bl1  = (const float*)d_in[10];
    const float* Wl2  = (const float*)d_in[11];
    const float* bl2  = (const float*)d_in[12];
    float* out = (float*)d_out;

    const int n  = in_sizes[2];      // 100000
    const int nE = in_sizes[1] / 2;  // 3200000
    const int* src = ei;
    const int* dst = ei + nE;

    const int NBKT  = (n + 255) >> 8;            // 391 buckets (256 nodes each)
    const int NBLKA = (nE + EPA - 1) / EPA;      // 391 pass-A blocks
    const int NG    = 1024;

    char* w = (char*)d_ws;
    auto alloc_f = [&](size_t cnt) { float* p = (float*)w; w += cnt * 4; return p; };
    auto alloc_i = [&](size_t cnt) { int*   p = (int*)w;   w += cnt * 4; return p; };

    float*    dinv   = alloc_f(n);
    int*      ideg   = alloc_i(n);
    int*      start  = alloc_i(n);
    int*      cnt    = alloc_i((size_t)NBKT * NBLKA);
    int*      po     = alloc_i((size_t)NBKT * NBLKA);
    int*      totals = alloc_i(NBKT);
    int*      bstart = alloc_i(NBKT + 1);
    int*      gstart = alloc_i(NG + 1);
    unsigned* ebuf   = (unsigned*)alloc_i(nE);   // 12.8 MB
    int*      col    = alloc_i(nE);              // 12.8 MB (contiguous after ebuf)
    // feature buffers
    float* Pd1 = alloc_f((size_t)n * 16);
    float* h1d = alloc_f((size_t)n * 16);
    float* a1  = alloc_f((size_t)n * 16);
    float* h2d = alloc_f((size_t)n * 32);
    float* a2  = Pd1;            // 32n over Pd1+h1d (both dead by agg3)
    float* h3  = (float*)ebuf;   // 64n over ebuf+col (dead by mm3)

    const int B = 256;
    auto g = [&](long long t) { return (int)((t + B - 1) / B); };

    // ---- CSR build: counting sort, zero global atomics
    k_histA<<<NBLKA, B, 0, stream>>>(dst, cnt, nE, NBKT, NBLKA);
    k_scanA<<<NBKT, MAXBKT, 0, stream>>>(cnt, po, totals, NBLKA);
    k_scanB<<<1, MAXBKT, 0, stream>>>(totals, bstart, NBKT, nE);
    k_scatA<<<NBLKA, B, 0, stream>>>(src, dst, po, bstart, ebuf, nE, NBKT, NBLKA);
    k_bsort<<<NBKT, 256, 0, stream>>>(ebuf, bstart, col, ideg, start, dinv, n);

    // ---- layer 1: Pd1 = dinv*(x@W1); h1d = dinv*relu(dinv*Agg(Pd1)+b1)
    k_mm<128, 16, 0><<<g((long long)n * 16), B, 0, stream>>>(x, W1, nullptr, dinv, Pd1, n);
    k_agg<16, 1><<<g((long long)n * 4), B, 0, stream>>>(Pd1, start, ideg, col, dinv, b1, h1d, n);

    // ---- layer 2: a1 = dinv*Agg(h1d); h2d = dinv*relu(a1@W2+b2)
    k_agg<16, 0><<<g((long long)n * 4), B, 0, stream>>>(h1d, start, ideg, col, dinv, nullptr, a1, n);
    k_mm<16, 32, 1><<<g((long long)n * 32), B, 0, stream>>>(a1, W2, b2, dinv, h2d, n);

    // ---- layer 3: a2 = dinv*Agg(h2d); h3 = relu(a2@W3+b3)
    k_agg<32, 0><<<g((long long)n * 8), B, 0, stream>>>(h2d, start, ideg, col, dinv, nullptr, a2, n);
    k_mm<32, 64, 2><<<g((long long)n * 64), B, 0, stream>>>(a2, W3, b3, dinv, h3, n);

    // ---- fused mean-pool + head (no atomics; batch is sorted)
    k_bounds<<<(NG + 1 + B - 1) / B, B, 0, stream>>>(batch, gstart, n, NG);
    k_poolhead<<<NG, 64, 0, stream>>>(h3, gstart, Wl1, bl1, Wl2, bl2, out);
}

// Round 6
// 373.735 us; speedup vs baseline: 2.0784x; 1.1338x over previous
//
#include <hip/hip_runtime.h>

// GCN forward: 3x GCNConv (symmetric norm, self-loops) + mean-pool + MLP head.
// R6: src-quartile-partitioned edge lists + multi-pass aggregation so each
//     pass's gather footprint (3.2 MB) fits a 4 MiB per-XCD L2.
//     (R5 counters: agg FETCH = 325 MB vs 12.8 MB working set = L2 thrash.)

constexpr int EPA    = 8192;  // edges per pass-A block
constexpr int MAXBKT = 512;   // LDS padding (NBKT = 391, NBLKA = 391)

// ---- pass A phase 1: per-block bucket histogram (LDS atomics only)
__global__ void k_histA(const int* __restrict__ dst, int* __restrict__ cnt,
                        int nE, int NBKT, int NBLKA) {
    __shared__ int hist[MAXBKT];
    for (int t = threadIdx.x; t < NBKT; t += blockDim.x) hist[t] = 0;
    __syncthreads();
    int base = blockIdx.x * EPA;
    int end = min(base + EPA, nE);
    for (int e = base + threadIdx.x; e < end; e += blockDim.x)
        atomicAdd(&hist[dst[e] >> 8], 1);
    __syncthreads();
    for (int t = threadIdx.x; t < NBKT; t += blockDim.x)
        cnt[t * NBLKA + blockIdx.x] = hist[t];
}

// ---- pass A phase 2a: per-bucket exclusive scan over blocks
__global__ void k_scanA(const int* __restrict__ cnt, int* __restrict__ po,
                        int* __restrict__ totals, int NBLKA) {
    __shared__ int sc[MAXBKT];
    int j = blockIdx.x, t = threadIdx.x;  // blockDim = MAXBKT
    int v = (t < NBLKA) ? cnt[j * NBLKA + t] : 0;
    sc[t] = v;
    __syncthreads();
    for (int off = 1; off < MAXBKT; off <<= 1) {
        int u = (t >= off) ? sc[t - off] : 0;
        __syncthreads();
        sc[t] += u;
        __syncthreads();
    }
    if (t < NBLKA) po[j * NBLKA + t] = sc[t] - v;
    if (t == MAXBKT - 1) totals[j] = sc[t];
}

// ---- pass A phase 2b: exclusive scan of bucket totals
__global__ void k_scanB(const int* __restrict__ totals, int* __restrict__ bstart,
                        int NBKT, int nE) {
    __shared__ int sc[MAXBKT];
    int t = threadIdx.x;
    int v = (t < NBKT) ? totals[t] : 0;
    sc[t] = v;
    __syncthreads();
    for (int off = 1; off < MAXBKT; off <<= 1) {
        int u = (t >= off) ? sc[t - off] : 0;
        __syncthreads();
        sc[t] += u;
        __syncthreads();
    }
    if (t < NBKT) bstart[t] = sc[t] - v;
    if (t == 0) bstart[NBKT] = nE;
}

// ---- pass A phase 3: scatter packed entries into disjoint per-(block,bucket)
//      ranges; LDS cursors, plain cached writes.
__global__ void k_scatA(const int* __restrict__ src, const int* __restrict__ dst,
                        const int* __restrict__ po, const int* __restrict__ bstart,
                        unsigned* __restrict__ ebuf, int nE, int NBKT, int NBLKA) {
    __shared__ int cur[MAXBKT];
    for (int t = threadIdx.x; t < NBKT; t += blockDim.x)
        cur[t] = po[t * NBLKA + blockIdx.x] + bstart[t];
    __syncthreads();
    int base = blockIdx.x * EPA;
    int end = min(base + EPA, nE);
    for (int e = base + threadIdx.x; e < end; e += blockDim.x) {
        int s = src[e], d = dst[e];
        int pos = atomicAdd(&cur[d >> 8], 1);  // LDS
        ebuf[pos] = ((unsigned)(d & 255) << 17) | (unsigned)s;
    }
}

// ---- pass B: per-bucket counting sort by (node, src-quartile).
//      Writes start/dinv/col and packed per-quartile counts poff.
__global__ void k_bsort(const unsigned* __restrict__ ebuf, const int* __restrict__ bstart,
                        int* __restrict__ col, int* __restrict__ start,
                        float* __restrict__ dinv, unsigned* __restrict__ poff,
                        int n, int qsz) {
    __shared__ int hist4[1024], cur4[1024], tot[256], excl[256];
    int b = blockIdx.x, t = threadIdx.x;
    int ebase = bstart[b], eend = bstart[b + 1];
    hist4[t] = 0; hist4[t + 256] = 0; hist4[t + 512] = 0; hist4[t + 768] = 0;
    __syncthreads();
    for (int e = ebase + t; e < eend; e += 256) {
        unsigned u = ebuf[e];
        int ln = u >> 17, s = (int)(u & 0x1FFFFu);
        atomicAdd(&hist4[ln * 4 + (s / qsz)], 1);  // LDS
    }
    __syncthreads();
    int c0 = hist4[t * 4], c1 = hist4[t * 4 + 1];
    int c2 = hist4[t * 4 + 2], c3 = hist4[t * 4 + 3];
    int v = c0 + c1 + c2 + c3;
    tot[t] = v; excl[t] = v;
    __syncthreads();
    for (int off = 1; off < 256; off <<= 1) {
        int u = (t >= off) ? excl[t - off] : 0;
        __syncthreads();
        excl[t] += u;
        __syncthreads();
    }
    int ex = excl[t] - v;  // exclusive within bucket
    int sbase = ebase + ex;
    cur4[t * 4]     = sbase;
    cur4[t * 4 + 1] = sbase + c0;
    cur4[t * 4 + 2] = sbase + c0 + c1;
    cur4[t * 4 + 3] = sbase + c0 + c1 + c2;
    int node = (b << 8) + t;
    if (node < n) {
        start[node] = sbase;
        dinv[node] = rsqrtf((float)(v + 1));
        poff[node] = (unsigned)c0 | ((unsigned)c1 << 8) |
                     ((unsigned)c2 << 16) | ((unsigned)c3 << 24);
    }
    __syncthreads();
    for (int e = ebase + t; e < eend; e += 256) {
        unsigned u = ebuf[e];
        int ln = u >> 17, s = (int)(u & 0x1FFFFu);
        int pos = atomicAdd(&cur4[ln * 4 + (s / qsz)], 1);  // LDS
        col[pos] = s;
    }
}

// ---- multi-pass aggregation over dinv-prescaled rows T.
//      Pass covers src-quartiles [P0,P1). FIRST pass seeds with the self term;
//      LAST pass applies the epilogue; middle passes accumulate raw in `out`.
//   EPI 0: out = dinv[i]*total ; EPI 1: out = dinv[i]*relu(dinv[i]*total + b)
template <int F, int P0, int P1, int EPI>
__global__ void k_agg(const float* __restrict__ T, const int* __restrict__ start,
                      const unsigned* __restrict__ poff, const int* __restrict__ col,
                      const float* __restrict__ dinv, const float* __restrict__ bias,
                      float* __restrict__ out, int n) {
    constexpr int TPN = F / 4;
    constexpr bool FIRST = (P0 == 0), LAST = (P1 == 4);
    int idx = blockIdx.x * blockDim.x + threadIdx.x;
    int i = idx / TPN;
    int q = idx % TPN;
    if (i >= n) return;
    unsigned pk = poff[i];
    int cs[4] = {(int)(pk & 255u), (int)((pk >> 8) & 255u),
                 (int)((pk >> 16) & 255u), (int)(pk >> 24)};
    int off = 0;
    #pragma unroll
    for (int p = 0; p < P0; ++p) off += cs[p];
    int len = 0;
    #pragma unroll
    for (int p = P0; p < P1; ++p) len += cs[p];
    int base = start[i] + off;
    const float4* T4 = (const float4*)T;
    float4* O4 = (float4*)out;
    float4 acc = FIRST ? T4[(size_t)i * TPN + q] : O4[(size_t)i * TPN + q];
    int k = 0;
    for (; k + 4 <= len; k += 4) {
        int s0 = col[base + k],     s1 = col[base + k + 1];
        int s2 = col[base + k + 2], s3 = col[base + k + 3];
        float4 v0 = T4[(size_t)s0 * TPN + q];
        float4 v1 = T4[(size_t)s1 * TPN + q];
        float4 v2 = T4[(size_t)s2 * TPN + q];
        float4 v3 = T4[(size_t)s3 * TPN + q];
        acc.x += v0.x + v1.x + v2.x + v3.x;
        acc.y += v0.y + v1.y + v2.y + v3.y;
        acc.z += v0.z + v1.z + v2.z + v3.z;
        acc.w += v0.w + v1.w + v2.w + v3.w;
    }
    for (; k < len; ++k) {
        float4 v = T4[(size_t)col[base + k] * TPN + q];
        acc.x += v.x; acc.y += v.y; acc.z += v.z; acc.w += v.w;
    }
    if (LAST) {
        float d = dinv[i];
        float4 o;
        if (EPI == 0) {
            o.x = d * acc.x; o.y = d * acc.y; o.z = d * acc.z; o.w = d * acc.w;
        } else {
            float4 b = ((const float4*)bias)[q];
            o.x = d * fmaxf(d * acc.x + b.x, 0.0f);
            o.y = d * fmaxf(d * acc.y + b.y, 0.0f);
            o.z = d * fmaxf(d * acc.z + b.z, 0.0f);
            o.w = d * fmaxf(d * acc.w + b.w, 0.0f);
        }
        O4[(size_t)i * TPN + q] = o;
    } else {
        O4[(size_t)i * TPN + q] = acc;
    }
}

// ---- dense per-node matmul; EPI 0: dinv*mm ; 1: dinv*relu(mm+b) ; 2: relu(mm+b)
template <int K, int F, int EPI>
__global__ void k_mm(const float* __restrict__ H, const float* __restrict__ W,
                     const float* __restrict__ b, const float* __restrict__ dinv,
                     float* __restrict__ out, int n) {
    __shared__ float sW[K * F];
    for (int t = threadIdx.x; t < K * F; t += blockDim.x) sW[t] = W[t];
    __syncthreads();
    int idx = blockIdx.x * blockDim.x + threadIdx.x;
    int i = idx / F, f = idx % F;
    if (i >= n) return;
    const float* h = H + (size_t)i * K;
    float acc = (EPI == 0) ? 0.0f : b[f];
    #pragma unroll 8
    for (int k = 0; k < K; ++k) acc += h[k] * sW[k * F + f];
    if (EPI != 0) acc = fmaxf(acc, 0.0f);
    if (EPI != 2) acc *= dinv[i];
    out[(size_t)i * F + f] = acc;
}

// ---- fused mean-pool + MLP head: one block (64 threads) per graph.
//      Graph bounds found by in-block binary search (batch is sorted).
__global__ void k_poolhead(const float* __restrict__ h3, const int* __restrict__ batch,
                           const float* __restrict__ Wl1, const float* __restrict__ bl1,
                           const float* __restrict__ Wl2, const float* __restrict__ bl2,
                           float* __restrict__ out, int n) {
    int g = blockIdx.x, t = threadIdx.x;
    __shared__ int sb[2];
    __shared__ float mean[64], hid[64];
    if (t < 2) {
        int target = g + t;
        int lo = 0, hi = n;
        while (lo < hi) {
            int mid = (lo + hi) >> 1;
            if (batch[mid] < target) lo = mid + 1; else hi = mid;
        }
        sb[t] = lo;
    }
    __syncthreads();
    int s = sb[0], e = sb[1];
    float acc = 0.0f;
    for (int i = s; i < e; ++i) acc += h3[(size_t)i * 64 + t];
    float c = fmaxf((float)(e - s), 1.0f);
    mean[t] = acc / c;
    __syncthreads();
    float a = bl1[t];
    #pragma unroll 8
    for (int k = 0; k < 64; ++k) a += mean[k] * Wl1[k * 64 + t];
    hid[t] = fmaxf(a, 0.0f);
    __syncthreads();
    if (t < 2) {
        float o = bl2[t];
        #pragma unroll 8
        for (int k = 0; k < 64; ++k) o += hid[k] * Wl2[k * 2 + t];
        out[g * 2 + t] = o;
    }
}

extern "C" void kernel_launch(void* const* d_in, const int* in_sizes, int n_in,
                              void* d_out, int out_size, void* d_ws, size_t ws_size,
                              hipStream_t stream) {
    const float* x    = (const float*)d_in[0];
    const int*   ei   = (const int*)d_in[1];
    const int*   batch= (const int*)d_in[2];
    const float* W1   = (const float*)d_in[3];
    const float* b1   = (const float*)d_in[4];
    const float* W2   = (const float*)d_in[5];
    const float* b2   = (const float*)d_in[6];
    const float* W3   = (const float*)d_in[7];
    const float* b3   = (const float*)d_in[8];
    const float* Wl1  = (const float*)d_in[9];
    const float* bl1  = (const float*)d_in[10];
    const float* Wl2  = (const float*)d_in[11];
    const float* bl2  = (const float*)d_in[12];
    float* out = (float*)d_out;

    const int n  = in_sizes[2];      // 100000
    const int nE = in_sizes[1] / 2;  // 3200000
    const int* src = ei;
    const int* dst = ei + nE;

    const int NBKT  = (n + 255) >> 8;        // 391 buckets (256 nodes each)
    const int NBLKA = (nE + EPA - 1) / EPA;  // 391 pass-A blocks
    const int NG    = 1024;
    const int qsz   = (n + 3) / 4;           // src-quartile size

    char* w = (char*)d_ws;
    auto alloc_f = [&](size_t cnt) { float* p = (float*)w; w += cnt * 4; return p; };
    auto alloc_i = [&](size_t cnt) { int*   p = (int*)w;   w += cnt * 4; return p; };

    float*    dinv   = alloc_f(n);
    int*      start  = alloc_i(n);
    unsigned* poff   = (unsigned*)alloc_i(n);
    int*      cnt    = alloc_i((size_t)NBKT * NBLKA);
    int*      po     = alloc_i((size_t)NBKT * NBLKA);
    int*      totals = alloc_i(NBKT);
    int*      bstart = alloc_i(NBKT + 1);
    unsigned* ebuf   = (unsigned*)alloc_i(nE);   // 12.8 MB
    int*      col    = alloc_i(nE);              // 12.8 MB (contiguous after ebuf)
    float* Pd1 = alloc_f((size_t)n * 16);
    float* h1d = alloc_f((size_t)n * 16);
    float* a1  = alloc_f((size_t)n * 16);
    float* h2d = alloc_f((size_t)n * 32);
    float* a2  = Pd1;            // 32n over Pd1+h1d (both dead by agg3)
    float* h3  = (float*)ebuf;   // 64n over ebuf+col (dead by mm3)

    const int B = 256;
    auto g = [&](long long t) { return (int)((t + B - 1) / B); };

    // ---- CSR build: counting sort, zero global atomics
    k_histA<<<NBLKA, B, 0, stream>>>(dst, cnt, nE, NBKT, NBLKA);
    k_scanA<<<NBKT, MAXBKT, 0, stream>>>(cnt, po, totals, NBLKA);
    k_scanB<<<1, MAXBKT, 0, stream>>>(totals, bstart, NBKT, nE);
    k_scatA<<<NBLKA, B, 0, stream>>>(src, dst, po, bstart, ebuf, nE, NBKT, NBLKA);
    k_bsort<<<NBKT, 256, 0, stream>>>(ebuf, bstart, col, start, dinv, poff, n, qsz);

    // ---- layer 1: Pd1 = dinv*(x@W1); h1d = dinv*relu(dinv*Agg(Pd1)+b1)
    k_mm<128, 16, 0><<<g((long long)n * 16), B, 0, stream>>>(x, W1, nullptr, dinv, Pd1, n);
    k_agg<16, 0, 2, 1><<<g((long long)n * 4), B, 0, stream>>>(Pd1, start, poff, col, dinv, b1, h1d, n);
    k_agg<16, 2, 4, 1><<<g((long long)n * 4), B, 0, stream>>>(Pd1, start, poff, col, dinv, b1, h1d, n);

    // ---- layer 2: a1 = dinv*Agg(h1d); h2d = dinv*relu(a1@W2+b2)
    k_agg<16, 0, 2, 0><<<g((long long)n * 4), B, 0, stream>>>(h1d, start, poff, col, dinv, nullptr, a1, n);
    k_agg<16, 2, 4, 0><<<g((long long)n * 4), B, 0, stream>>>(h1d, start, poff, col, dinv, nullptr, a1, n);
    k_mm<16, 32, 1><<<g((long long)n * 32), B, 0, stream>>>(a1, W2, b2, dinv, h2d, n);

    // ---- layer 3: a2 = dinv*Agg(h2d); h3 = relu(a2@W3+b3)
    k_agg<32, 0, 1, 0><<<g((long long)n * 8), B, 0, stream>>>(h2d, start, poff, col, dinv, nullptr, a2, n);
    k_agg<32, 1, 2, 0><<<g((long long)n * 8), B, 0, stream>>>(h2d, start, poff, col, dinv, nullptr, a2, n);
    k_agg<32, 2, 3, 0><<<g((long long)n * 8), B, 0, stream>>>(h2d, start, poff, col, dinv, nullptr, a2, n);
    k_agg<32, 3, 4, 0><<<g((long long)n * 8), B, 0, stream>>>(h2d, start, poff, col, dinv, nullptr, a2, n);
    k_mm<32, 64, 2><<<g((long long)n * 64), B, 0, stream>>>(a2, W3, b3, dinv, h3, n);

    // ---- fused mean-pool + head (no atomics; batch is sorted)
    k_poolhead<<<NG, 64, 0, stream>>>(h3, batch, Wl1, bl1, Wl2, bl2, out, n);
}

// Round 7
// 351.107 us; speedup vs baseline: 2.2123x; 1.0644x over previous
//
#include <hip/hip_runtime.h>

// GCN forward: 3x GCNConv (symmetric norm, self-loops) + mean-pool + MLP head.
// R7: wave-per-node register-W matmuls (R6 counters: thread-per-output mm was
//     memory-instruction bound, 52us for 34MB). CSR build + quartile-partition
//     agg unchanged from R6.

constexpr int EPA    = 8192;  // edges per pass-A block
constexpr int MAXBKT = 512;   // LDS padding (NBKT = 391, NBLKA = 391)

// ---- pass A phase 1: per-block bucket histogram (LDS atomics only)
__global__ void k_histA(const int* __restrict__ dst, int* __restrict__ cnt,
                        int nE, int NBKT, int NBLKA) {
    __shared__ int hist[MAXBKT];
    for (int t = threadIdx.x; t < NBKT; t += blockDim.x) hist[t] = 0;
    __syncthreads();
    int base = blockIdx.x * EPA;
    int end = min(base + EPA, nE);
    for (int e = base + threadIdx.x; e < end; e += blockDim.x)
        atomicAdd(&hist[dst[e] >> 8], 1);
    __syncthreads();
    for (int t = threadIdx.x; t < NBKT; t += blockDim.x)
        cnt[t * NBLKA + blockIdx.x] = hist[t];
}

// ---- pass A phase 2a: per-bucket exclusive scan over blocks
__global__ void k_scanA(const int* __restrict__ cnt, int* __restrict__ po,
                        int* __restrict__ totals, int NBLKA) {
    __shared__ int sc[MAXBKT];
    int j = blockIdx.x, t = threadIdx.x;  // blockDim = MAXBKT
    int v = (t < NBLKA) ? cnt[j * NBLKA + t] : 0;
    sc[t] = v;
    __syncthreads();
    for (int off = 1; off < MAXBKT; off <<= 1) {
        int u = (t >= off) ? sc[t - off] : 0;
        __syncthreads();
        sc[t] += u;
        __syncthreads();
    }
    if (t < NBLKA) po[j * NBLKA + t] = sc[t] - v;
    if (t == MAXBKT - 1) totals[j] = sc[t];
}

// ---- pass A phase 2b: exclusive scan of bucket totals
__global__ void k_scanB(const int* __restrict__ totals, int* __restrict__ bstart,
                        int NBKT, int nE) {
    __shared__ int sc[MAXBKT];
    int t = threadIdx.x;
    int v = (t < NBKT) ? totals[t] : 0;
    sc[t] = v;
    __syncthreads();
    for (int off = 1; off < MAXBKT; off <<= 1) {
        int u = (t >= off) ? sc[t - off] : 0;
        __syncthreads();
        sc[t] += u;
        __syncthreads();
    }
    if (t < NBKT) bstart[t] = sc[t] - v;
    if (t == 0) bstart[NBKT] = nE;
}

// ---- pass A phase 3: scatter packed entries into disjoint per-(block,bucket)
//      ranges; LDS cursors, plain cached writes.
__global__ void k_scatA(const int* __restrict__ src, const int* __restrict__ dst,
                        const int* __restrict__ po, const int* __restrict__ bstart,
                        unsigned* __restrict__ ebuf, int nE, int NBKT, int NBLKA) {
    __shared__ int cur[MAXBKT];
    for (int t = threadIdx.x; t < NBKT; t += blockDim.x)
        cur[t] = po[t * NBLKA + blockIdx.x] + bstart[t];
    __syncthreads();
    int base = blockIdx.x * EPA;
    int end = min(base + EPA, nE);
    for (int e = base + threadIdx.x; e < end; e += blockDim.x) {
        int s = src[e], d = dst[e];
        int pos = atomicAdd(&cur[d >> 8], 1);  // LDS
        ebuf[pos] = ((unsigned)(d & 255) << 17) | (unsigned)s;
    }
}

// ---- pass B: per-bucket counting sort by (node, src-quartile).
//      Writes start/dinv/col and packed per-quartile counts poff.
__global__ void k_bsort(const unsigned* __restrict__ ebuf, const int* __restrict__ bstart,
                        int* __restrict__ col, int* __restrict__ start,
                        float* __restrict__ dinv, unsigned* __restrict__ poff,
                        int n, int qsz) {
    __shared__ int hist4[1024], cur4[1024], excl[256];
    int b = blockIdx.x, t = threadIdx.x;
    int ebase = bstart[b], eend = bstart[b + 1];
    hist4[t] = 0; hist4[t + 256] = 0; hist4[t + 512] = 0; hist4[t + 768] = 0;
    __syncthreads();
    for (int e = ebase + t; e < eend; e += 256) {
        unsigned u = ebuf[e];
        int ln = u >> 17, s = (int)(u & 0x1FFFFu);
        atomicAdd(&hist4[ln * 4 + (s / qsz)], 1);  // LDS
    }
    __syncthreads();
    int c0 = hist4[t * 4], c1 = hist4[t * 4 + 1];
    int c2 = hist4[t * 4 + 2], c3 = hist4[t * 4 + 3];
    int v = c0 + c1 + c2 + c3;
    excl[t] = v;
    __syncthreads();
    for (int off = 1; off < 256; off <<= 1) {
        int u = (t >= off) ? excl[t - off] : 0;
        __syncthreads();
        excl[t] += u;
        __syncthreads();
    }
    int ex = excl[t] - v;  // exclusive within bucket
    int sbase = ebase + ex;
    cur4[t * 4]     = sbase;
    cur4[t * 4 + 1] = sbase + c0;
    cur4[t * 4 + 2] = sbase + c0 + c1;
    cur4[t * 4 + 3] = sbase + c0 + c1 + c2;
    int node = (b << 8) + t;
    if (node < n) {
        start[node] = sbase;
        dinv[node] = rsqrtf((float)(v + 1));
        poff[node] = (unsigned)c0 | ((unsigned)c1 << 8) |
                     ((unsigned)c2 << 16) | ((unsigned)c3 << 24);
    }
    __syncthreads();
    for (int e = ebase + t; e < eend; e += 256) {
        unsigned u = ebuf[e];
        int ln = u >> 17, s = (int)(u & 0x1FFFFu);
        int pos = atomicAdd(&cur4[ln * 4 + (s / qsz)], 1);  // LDS
        col[pos] = s;
    }
}

// ---- multi-pass aggregation over dinv-prescaled rows T.
//      Pass covers src-quartiles [P0,P1). FIRST pass seeds with the self term;
//      LAST pass applies the epilogue; middle passes accumulate raw in `out`.
//   EPI 0: out = dinv[i]*total ; EPI 1: out = dinv[i]*relu(dinv[i]*total + b)
template <int F, int P0, int P1, int EPI>
__global__ void k_agg(const float* __restrict__ T, const int* __restrict__ start,
                      const unsigned* __restrict__ poff, const int* __restrict__ col,
                      const float* __restrict__ dinv, const float* __restrict__ bias,
                      float* __restrict__ out, int n) {
    constexpr int TPN = F / 4;
    constexpr bool FIRST = (P0 == 0), LAST = (P1 == 4);
    int idx = blockIdx.x * blockDim.x + threadIdx.x;
    int i = idx / TPN;
    int q = idx % TPN;
    if (i >= n) return;
    unsigned pk = poff[i];
    int cs[4] = {(int)(pk & 255u), (int)((pk >> 8) & 255u),
                 (int)((pk >> 16) & 255u), (int)(pk >> 24)};
    int off = 0;
    #pragma unroll
    for (int p = 0; p < P0; ++p) off += cs[p];
    int len = 0;
    #pragma unroll
    for (int p = P0; p < P1; ++p) len += cs[p];
    int base = start[i] + off;
    const float4* T4 = (const float4*)T;
    float4* O4 = (float4*)out;
    float4 acc = FIRST ? T4[(size_t)i * TPN + q] : O4[(size_t)i * TPN + q];
    int k = 0;
    for (; k + 4 <= len; k += 4) {
        int s0 = col[base + k],     s1 = col[base + k + 1];
        int s2 = col[base + k + 2], s3 = col[base + k + 3];
        float4 v0 = T4[(size_t)s0 * TPN + q];
        float4 v1 = T4[(size_t)s1 * TPN + q];
        float4 v2 = T4[(size_t)s2 * TPN + q];
        float4 v3 = T4[(size_t)s3 * TPN + q];
        acc.x += v0.x + v1.x + v2.x + v3.x;
        acc.y += v0.y + v1.y + v2.y + v3.y;
        acc.z += v0.z + v1.z + v2.z + v3.z;
        acc.w += v0.w + v1.w + v2.w + v3.w;
    }
    for (; k < len; ++k) {
        float4 v = T4[(size_t)col[base + k] * TPN + q];
        acc.x += v.x; acc.y += v.y; acc.z += v.z; acc.w += v.w;
    }
    if (LAST) {
        float d = dinv[i];
        float4 o;
        if (EPI == 0) {
            o.x = d * acc.x; o.y = d * acc.y; o.z = d * acc.z; o.w = d * acc.w;
        } else {
            float4 b = ((const float4*)bias)[q];
            o.x = d * fmaxf(d * acc.x + b.x, 0.0f);
            o.y = d * fmaxf(d * acc.y + b.y, 0.0f);
            o.z = d * fmaxf(d * acc.z + b.z, 0.0f);
            o.w = d * fmaxf(d * acc.w + b.w, 0.0f);
        }
        O4[(size_t)i * TPN + q] = o;
    } else {
        O4[(size_t)i * TPN + q] = acc;
    }
}

// ---- mm1: Pd1 = dinv * (x @ W1), K=128 F=16.
//      Wave per node: lane = kc*16+f (kc = K-chunk). W chunk in 32 VGPRs.
__global__ void k_mm1(const float* __restrict__ H, const float* __restrict__ W,
                      const float* __restrict__ dinv, float* __restrict__ out,
                      int n, int nwaves) {
    int lane = threadIdx.x & 63;
    int wid = (blockIdx.x * blockDim.x + threadIdx.x) >> 6;
    int f = lane & 15, kc = lane >> 4;  // kc in [0,4)
    float wcol[32];
    #pragma unroll
    for (int kk = 0; kk < 32; ++kk) wcol[kk] = W[(kc * 32 + kk) * 16 + f];
    for (int i = wid; i < n; i += nwaves) {
        const float4* h4 = (const float4*)(H + (size_t)i * 128);
        float acc = 0.0f;
        #pragma unroll
        for (int j = 0; j < 8; ++j) {
            float4 hv = h4[kc * 8 + j];
            acc += hv.x * wcol[j * 4]     + hv.y * wcol[j * 4 + 1]
                 + hv.z * wcol[j * 4 + 2] + hv.w * wcol[j * 4 + 3];
        }
        acc += __shfl_xor(acc, 16);
        acc += __shfl_xor(acc, 32);
        if (kc == 0) out[(size_t)i * 16 + f] = acc * dinv[i];
    }
}

// ---- mm2: h2d = dinv * relu(a1 @ W2 + b2), K=16 F=32.
//      Wave per 2 nodes: lane = p*32+f. W column in 16 VGPRs.
__global__ void k_mm2(const float* __restrict__ H, const float* __restrict__ W,
                      const float* __restrict__ b, const float* __restrict__ dinv,
                      float* __restrict__ out, int n, int nwaves) {
    int lane = threadIdx.x & 63;
    int wid = (blockIdx.x * blockDim.x + threadIdx.x) >> 6;
    int f = lane & 31, p = lane >> 5;
    float wcol[16];
    #pragma unroll
    for (int k = 0; k < 16; ++k) wcol[k] = W[k * 32 + f];
    float bias = b[f];
    for (int i0 = wid * 2; i0 < n; i0 += nwaves * 2) {
        int i = i0 + p;
        if (i < n) {
            const float4* h4 = (const float4*)(H + (size_t)i * 16);
            float acc = bias;
            #pragma unroll
            for (int j = 0; j < 4; ++j) {
                float4 hv = h4[j];
                acc += hv.x * wcol[j * 4]     + hv.y * wcol[j * 4 + 1]
                     + hv.z * wcol[j * 4 + 2] + hv.w * wcol[j * 4 + 3];
            }
            out[(size_t)i * 32 + f] = fmaxf(acc, 0.0f) * dinv[i];
        }
    }
}

// ---- mm3: h3 = relu(a2 @ W3 + b3), K=32 F=64.
//      Wave per node: lane = f. W column in 32 VGPRs.
__global__ void k_mm3(const float* __restrict__ H, const float* __restrict__ W,
                      const float* __restrict__ b, float* __restrict__ out,
                      int n, int nwaves) {
    int lane = threadIdx.x & 63;
    int wid = (blockIdx.x * blockDim.x + threadIdx.x) >> 6;
    float wcol[32];
    #pragma unroll
    for (int k = 0; k < 32; ++k) wcol[k] = W[k * 64 + lane];
    float bias = b[lane];
    for (int i = wid; i < n; i += nwaves) {
        const float4* h4 = (const float4*)(H + (size_t)i * 32);
        float acc = bias;
        #pragma unroll
        for (int j = 0; j < 8; ++j) {
            float4 hv = h4[j];
            acc += hv.x * wcol[j * 4]     + hv.y * wcol[j * 4 + 1]
                 + hv.z * wcol[j * 4 + 2] + hv.w * wcol[j * 4 + 3];
        }
        out[(size_t)i * 64 + lane] = fmaxf(acc, 0.0f);
    }
}

// ---- fused mean-pool + MLP head: one block (64 threads) per graph.
__global__ void k_poolhead(const float* __restrict__ h3, const int* __restrict__ batch,
                           const float* __restrict__ Wl1, const float* __restrict__ bl1,
                           const float* __restrict__ Wl2, const float* __restrict__ bl2,
                           float* __restrict__ out, int n) {
    int g = blockIdx.x, t = threadIdx.x;
    __shared__ int sb[2];
    __shared__ float mean[64], hid[64];
    if (t < 2) {
        int target = g + t;
        int lo = 0, hi = n;
        while (lo < hi) {
            int mid = (lo + hi) >> 1;
            if (batch[mid] < target) lo = mid + 1; else hi = mid;
        }
        sb[t] = lo;
    }
    __syncthreads();
    int s = sb[0], e = sb[1];
    float acc = 0.0f;
    for (int i = s; i < e; ++i) acc += h3[(size_t)i * 64 + t];
    float c = fmaxf((float)(e - s), 1.0f);
    mean[t] = acc / c;
    __syncthreads();
    float a = bl1[t];
    #pragma unroll 8
    for (int k = 0; k < 64; ++k) a += mean[k] * Wl1[k * 64 + t];
    hid[t] = fmaxf(a, 0.0f);
    __syncthreads();
    if (t < 2) {
        float o = bl2[t];
        #pragma unroll 8
        for (int k = 0; k < 64; ++k) o += hid[k] * Wl2[k * 2 + t];
        out[g * 2 + t] = o;
    }
}

extern "C" void kernel_launch(void* const* d_in, const int* in_sizes, int n_in,
                              void* d_out, int out_size, void* d_ws, size_t ws_size,
                              hipStream_t stream) {
    const float* x    = (const float*)d_in[0];
    const int*   ei   = (const int*)d_in[1];
    const int*   batch= (const int*)d_in[2];
    const float* W1   = (const float*)d_in[3];
    const float* b1   = (const float*)d_in[4];
    const float* W2   = (const float*)d_in[5];
    const float* b2   = (const float*)d_in[6];
    const float* W3   = (const float*)d_in[7];
    const float* b3   = (const float*)d_in[8];
    const float* Wl1  = (const float*)d_in[9];
    const float* bl1  = (const float*)d_in[10];
    const float* Wl2  = (const float*)d_in[11];
    const float* bl2  = (const float*)d_in[12];
    float* out = (float*)d_out;

    const int n  = in_sizes[2];      // 100000
    const int nE = in_sizes[1] / 2;  // 3200000
    const int* src = ei;
    const int* dst = ei + nE;

    const int NBKT  = (n + 255) >> 8;        // 391 buckets (256 nodes each)
    const int NBLKA = (nE + EPA - 1) / EPA;  // 391 pass-A blocks
    const int NG    = 1024;
    const int qsz   = (n + 3) / 4;           // src-quartile size

    char* w = (char*)d_ws;
    auto alloc_f = [&](size_t cnt) { float* p = (float*)w; w += cnt * 4; return p; };
    auto alloc_i = [&](size_t cnt) { int*   p = (int*)w;   w += cnt * 4; return p; };

    float*    dinv   = alloc_f(n);
    int*      start  = alloc_i(n);
    unsigned* poff   = (unsigned*)alloc_i(n);
    int*      cnt    = alloc_i((size_t)NBKT * NBLKA);
    int*      po     = alloc_i((size_t)NBKT * NBLKA);
    int*      totals = alloc_i(NBKT);
    int*      bstart = alloc_i(NBKT + 1);
    unsigned* ebuf   = (unsigned*)alloc_i(nE);   // 12.8 MB
    int*      col    = alloc_i(nE);              // 12.8 MB (contiguous after ebuf)
    float* Pd1 = alloc_f((size_t)n * 16);
    float* h1d = alloc_f((size_t)n * 16);
    float* a1  = alloc_f((size_t)n * 16);
    float* h2d = alloc_f((size_t)n * 32);
    float* a2  = Pd1;            // 32n over Pd1+h1d (both dead by agg3)
    float* h3  = (float*)ebuf;   // 64n over ebuf+col (dead by mm3)

    const int B = 256;
    auto g = [&](long long t) { return (int)((t + B - 1) / B); };
    const int MMBLK = 1024;                 // 4096 waves for the mm kernels
    const int NW = MMBLK * (B / 64);

    // ---- CSR build: counting sort, zero global atomics
    k_histA<<<NBLKA, B, 0, stream>>>(dst, cnt, nE, NBKT, NBLKA);
    k_scanA<<<NBKT, MAXBKT, 0, stream>>>(cnt, po, totals, NBLKA);
    k_scanB<<<1, MAXBKT, 0, stream>>>(totals, bstart, NBKT, nE);
    k_scatA<<<NBLKA, B, 0, stream>>>(src, dst, po, bstart, ebuf, nE, NBKT, NBLKA);
    k_bsort<<<NBKT, 256, 0, stream>>>(ebuf, bstart, col, start, dinv, poff, n, qsz);

    // ---- layer 1: Pd1 = dinv*(x@W1); h1d = dinv*relu(dinv*Agg(Pd1)+b1)
    k_mm1<<<MMBLK, B, 0, stream>>>(x, W1, dinv, Pd1, n, NW);
    k_agg<16, 0, 2, 1><<<g((long long)n * 4), B, 0, stream>>>(Pd1, start, poff, col, dinv, b1, h1d, n);
    k_agg<16, 2, 4, 1><<<g((long long)n * 4), B, 0, stream>>>(Pd1, start, poff, col, dinv, b1, h1d, n);

    // ---- layer 2: a1 = dinv*Agg(h1d); h2d = dinv*relu(a1@W2+b2)
    k_agg<16, 0, 2, 0><<<g((long long)n * 4), B, 0, stream>>>(h1d, start, poff, col, dinv, nullptr, a1, n);
    k_agg<16, 2, 4, 0><<<g((long long)n * 4), B, 0, stream>>>(h1d, start, poff, col, dinv, nullptr, a1, n);
    k_mm2<<<MMBLK, B, 0, stream>>>(a1, W2, b2, dinv, h2d, n, NW);

    // ---- layer 3: a2 = dinv*Agg(h2d); h3 = relu(a2@W3+b3)
    k_agg<32, 0, 1, 0><<<g((long long)n * 8), B, 0, stream>>>(h2d, start, poff, col, dinv, nullptr, a2, n);
    k_agg<32, 1, 2, 0><<<g((long long)n * 8), B, 0, stream>>>(h2d, start, poff, col, dinv, nullptr, a2, n);
    k_agg<32, 2, 3, 0><<<g((long long)n * 8), B, 0, stream>>>(h2d, start, poff, col, dinv, nullptr, a2, n);
    k_agg<32, 3, 4, 0><<<g((long long)n * 8), B, 0, stream>>>(h2d, start, poff, col, dinv, nullptr, a2, n);
    k_mm3<<<MMBLK, B, 0, stream>>>(a2, W3, b3, h3, n, NW);

    // ---- fused mean-pool + head (no atomics; batch is sorted)
    k_poolhead<<<NG, 64, 0, stream>>>(h3, batch, Wl1, bl1, Wl2, bl2, out, n);
}

// Round 8
// 346.554 us; speedup vs baseline: 2.2414x; 1.0131x over previous
//
#include <hip/hip_runtime.h>

// GCN forward: 3x GCNConv (symmetric norm, self-loops) + mean-pool + MLP head.
// R8: (a) mm1 -> LDS-tiled coalesced staging (R7: broadcast loads, latency-bound
//     at 36% occupancy); (b) scatA -> in-block counting sort writing block-major
//     contiguous slabs (write amp 3.6x -> ~1x), bsort gathers per-bucket segments.

constexpr int EPA    = 8192;   // edges per scatA block
constexpr int MAXBKT = 512;    // padded bucket count (NBKT = 391)
constexpr int STASH  = 10240;  // bsort LDS stash entries (mean 8192, +23 sigma)

// ---- scatA: per-block histogram + local counting sort -> contiguous slab.
//      Exports per-(block,bucket) counts (cntT) and local offsets (po2T).
__global__ __launch_bounds__(512) void k_scatA(const int* __restrict__ src,
        const int* __restrict__ dst, int* __restrict__ cntT, int* __restrict__ po2T,
        unsigned* __restrict__ ebuf, int nE) {
    __shared__ int hist[MAXBKT], excl[MAXBKT], lcur[MAXBKT];
    int blk = blockIdx.x, t = threadIdx.x;
    hist[t] = 0;
    __syncthreads();
    int base = blk * EPA, end = min(base + EPA, nE);
    for (int e = base + t; e < end; e += 512)
        atomicAdd(&hist[dst[e] >> 8], 1);  // LDS
    __syncthreads();
    int v = hist[t];
    excl[t] = v;
    __syncthreads();
    for (int off = 1; off < 512; off <<= 1) {
        int u = (t >= off) ? excl[t - off] : 0;
        __syncthreads();
        excl[t] += u;
        __syncthreads();
    }
    int ex = excl[t] - v;  // exclusive local offset
    lcur[t] = ex;
    cntT[blk * MAXBKT + t] = v;   // coalesced
    po2T[blk * MAXBKT + t] = ex;  // coalesced
    __syncthreads();
    for (int e = base + t; e < end; e += 512) {
        int s = src[e], d = dst[e];            // L2-hot re-read
        int pos = atomicAdd(&lcur[d >> 8], 1); // LDS
        ebuf[base + pos] = ((unsigned)(d & 255) << 17) | (unsigned)s;  // 32KB window
    }
}

// ---- per-bucket totals (column sum of cntT)
__global__ void k_totals(const int* __restrict__ cntT, int* __restrict__ totals,
                         int NBLKA) {
    __shared__ int red[256];
    int b = blockIdx.x, t = threadIdx.x;
    int sum = 0;
    for (int blk = t; blk < NBLKA; blk += 256) sum += cntT[blk * MAXBKT + b];
    red[t] = sum;
    __syncthreads();
    for (int off = 128; off > 0; off >>= 1) {
        if (t < off) red[t] += red[t + off];
        __syncthreads();
    }
    if (t == 0) totals[b] = red[0];
}

// ---- exclusive scan of bucket totals -> global CSR bucket bases
__global__ void k_scanB(const int* __restrict__ totals, int* __restrict__ bstart,
                        int NBKT, int nE) {
    __shared__ int sc[MAXBKT];
    int t = threadIdx.x;
    int v = (t < NBKT) ? totals[t] : 0;
    sc[t] = v;
    __syncthreads();
    for (int off = 1; off < MAXBKT; off <<= 1) {
        int u = (t >= off) ? sc[t - off] : 0;
        __syncthreads();
        sc[t] += u;
        __syncthreads();
    }
    if (t < NBKT) bstart[t] = sc[t] - v;
    if (t == 0) bstart[NBKT] = nE;
}

// ---- bsort: gather this bucket's segments from the block-major slabs into an
//      LDS stash, then counting-sort by (node, src-quartile) -> CSR col.
__global__ __launch_bounds__(512) void k_bsort(const unsigned* __restrict__ ebuf,
        const int* __restrict__ cntT, const int* __restrict__ po2T,
        const int* __restrict__ bstart, int* __restrict__ col, int* __restrict__ start,
        float* __restrict__ dinv, unsigned* __restrict__ poff,
        int n, int qsz, int NBLKA) {
    __shared__ unsigned stash[STASH];
    __shared__ int slen[MAXBKT], soff[MAXBKT], spref[MAXBKT];
    __shared__ int hist4[1024], cur4[1024], excl[256];
    int b = blockIdx.x, t = threadIdx.x;
    int l = 0, o = 0;
    if (t < NBLKA) {
        l = cntT[t * MAXBKT + b];
        o = t * EPA + po2T[t * MAXBKT + b];
    }
    slen[t] = l; soff[t] = o; spref[t] = l;
    __syncthreads();
    for (int off = 1; off < 512; off <<= 1) {
        int u = (t >= off) ? spref[t - off] : 0;
        __syncthreads();
        spref[t] += u;
        __syncthreads();
    }
    int total = spref[511];
    int wv = t >> 6, lane = t & 63;  // 8 waves: wave per segment round-robin
    for (int s = wv; s < NBLKA; s += 8) {
        int sl = slen[s], so = soff[s], sp = spref[s] - sl;
        for (int j = lane; j < sl; j += 64)
            stash[sp + j] = ebuf[so + j];
    }
    hist4[t] = 0; hist4[t + 512] = 0;
    __syncthreads();
    for (int j = t; j < total; j += 512) {
        unsigned u = stash[j];
        int ln = u >> 17, s = (int)(u & 0x1FFFFu);
        atomicAdd(&hist4[ln * 4 + s / qsz], 1);  // LDS
    }
    __syncthreads();
    int c0 = 0, c1 = 0, c2 = 0, c3 = 0, v = 0;
    if (t < 256) {
        c0 = hist4[t * 4];     c1 = hist4[t * 4 + 1];
        c2 = hist4[t * 4 + 2]; c3 = hist4[t * 4 + 3];
        v = c0 + c1 + c2 + c3;
        excl[t] = v;
    }
    __syncthreads();
    for (int off = 1; off < 256; off <<= 1) {
        int u = (t >= off && t < 256) ? excl[t - off] : 0;
        __syncthreads();
        if (t < 256) excl[t] += u;
        __syncthreads();
    }
    if (t < 256) {
        int ebase = bstart[b];
        int sbase = ebase + excl[t] - v;
        cur4[t * 4]     = sbase;
        cur4[t * 4 + 1] = sbase + c0;
        cur4[t * 4 + 2] = sbase + c0 + c1;
        cur4[t * 4 + 3] = sbase + c0 + c1 + c2;
        int node = (b << 8) + t;
        if (node < n) {
            start[node] = sbase;
            dinv[node] = rsqrtf((float)(v + 1));
            poff[node] = (unsigned)c0 | ((unsigned)c1 << 8) |
                         ((unsigned)c2 << 16) | ((unsigned)c3 << 24);
        }
    }
    __syncthreads();
    for (int j = t; j < total; j += 512) {
        unsigned u = stash[j];
        int ln = u >> 17, s = (int)(u & 0x1FFFFu);
        int pos = atomicAdd(&cur4[ln * 4 + s / qsz], 1);  // LDS
        col[pos] = s;  // 32KB window per bucket
    }
}

// ---- multi-pass aggregation over dinv-prescaled rows T (unchanged from R7)
template <int F, int P0, int P1, int EPI>
__global__ void k_agg(const float* __restrict__ T, const int* __restrict__ start,
                      const unsigned* __restrict__ poff, const int* __restrict__ col,
                      const float* __restrict__ dinv, const float* __restrict__ bias,
                      float* __restrict__ out, int n) {
    constexpr int TPN = F / 4;
    constexpr bool FIRST = (P0 == 0), LAST = (P1 == 4);
    int idx = blockIdx.x * blockDim.x + threadIdx.x;
    int i = idx / TPN;
    int q = idx % TPN;
    if (i >= n) return;
    unsigned pk = poff[i];
    int cs[4] = {(int)(pk & 255u), (int)((pk >> 8) & 255u),
                 (int)((pk >> 16) & 255u), (int)(pk >> 24)};
    int off = 0;
    #pragma unroll
    for (int p = 0; p < P0; ++p) off += cs[p];
    int len = 0;
    #pragma unroll
    for (int p = P0; p < P1; ++p) len += cs[p];
    int base = start[i] + off;
    const float4* T4 = (const float4*)T;
    float4* O4 = (float4*)out;
    float4 acc = FIRST ? T4[(size_t)i * TPN + q] : O4[(size_t)i * TPN + q];
    int k = 0;
    for (; k + 4 <= len; k += 4) {
        int s0 = col[base + k],     s1 = col[base + k + 1];
        int s2 = col[base + k + 2], s3 = col[base + k + 3];
        float4 v0 = T4[(size_t)s0 * TPN + q];
        float4 v1 = T4[(size_t)s1 * TPN + q];
        float4 v2 = T4[(size_t)s2 * TPN + q];
        float4 v3 = T4[(size_t)s3 * TPN + q];
        acc.x += v0.x + v1.x + v2.x + v3.x;
        acc.y += v0.y + v1.y + v2.y + v3.y;
        acc.z += v0.z + v1.z + v2.z + v3.z;
        acc.w += v0.w + v1.w + v2.w + v3.w;
    }
    for (; k < len; ++k) {
        float4 v = T4[(size_t)col[base + k] * TPN + q];
        acc.x += v.x; acc.y += v.y; acc.z += v.z; acc.w += v.w;
    }
    if (LAST) {
        float d = dinv[i];
        float4 o;
        if (EPI == 0) {
            o.x = d * acc.x; o.y = d * acc.y; o.z = d * acc.z; o.w = d * acc.w;
        } else {
            float4 b = ((const float4*)bias)[q];
            o.x = d * fmaxf(d * acc.x + b.x, 0.0f);
            o.y = d * fmaxf(d * acc.y + b.y, 0.0f);
            o.z = d * fmaxf(d * acc.z + b.z, 0.0f);
            o.w = d * fmaxf(d * acc.w + b.w, 0.0f);
        }
        O4[(size_t)i * TPN + q] = o;
    } else {
        O4[(size_t)i * TPN + q] = acc;
    }
}

// ---- mm1: Pd1 = dinv * (x @ W1), K=128 F=16. LDS-tiled: 64 rows staged
//      coalesced, register-W compute from LDS broadcasts.
__global__ __launch_bounds__(256) void k_mm1(const float4* __restrict__ X4,
        const float4* __restrict__ W4, const float* __restrict__ dinv,
        float* __restrict__ out, int n) {
    __shared__ float4 xs[64 * 32];  // 32KB: 64 rows x 128 floats
    __shared__ float4 ws[512];      // 8KB: W1
    int t = threadIdx.x;
    int nb = blockIdx.x * 64;
    ws[t] = W4[t]; ws[t + 256] = W4[t + 256];
    int lim = min(64, n - nb);
    #pragma unroll
    for (int it = 0; it < 8; ++it) {
        int idx = it * 256 + t;
        if ((idx >> 5) < lim) xs[idx] = X4[(size_t)nb * 32 + idx];
    }
    __syncthreads();
    int lane = t & 63, wv = t >> 6;
    int f = lane & 15, kc = lane >> 4;
    float wcol[32];
    #pragma unroll
    for (int kk = 0; kk < 32; ++kk)
        wcol[kk] = ((const float*)ws)[(kc * 32 + kk) * 16 + f];
    for (int ln = wv * 16; ln < wv * 16 + 16; ++ln) {
        if (ln >= lim) break;
        int i = nb + ln;
        float acc = 0.0f;
        #pragma unroll
        for (int j = 0; j < 8; ++j) {
            float4 hv = xs[ln * 32 + kc * 8 + j];
            acc += hv.x * wcol[4 * j]     + hv.y * wcol[4 * j + 1]
                 + hv.z * wcol[4 * j + 2] + hv.w * wcol[4 * j + 3];
        }
        acc += __shfl_xor(acc, 16);
        acc += __shfl_xor(acc, 32);
        if (kc == 0) out[(size_t)i * 16 + f] = acc * dinv[i];
    }
}

// ---- mm2: h2d = dinv * relu(a1 @ W2 + b2), K=16 F=32 (R7)
__global__ void k_mm2(const float* __restrict__ H, const float* __restrict__ W,
                      const float* __restrict__ b, const float* __restrict__ dinv,
                      float* __restrict__ out, int n, int nwaves) {
    int lane = threadIdx.x & 63;
    int wid = (blockIdx.x * blockDim.x + threadIdx.x) >> 6;
    int f = lane & 31, p = lane >> 5;
    float wcol[16];
    #pragma unroll
    for (int k = 0; k < 16; ++k) wcol[k] = W[k * 32 + f];
    float bias = b[f];
    for (int i0 = wid * 2; i0 < n; i0 += nwaves * 2) {
        int i = i0 + p;
        if (i < n) {
            const float4* h4 = (const float4*)(H + (size_t)i * 16);
            float acc = bias;
            #pragma unroll
            for (int j = 0; j < 4; ++j) {
                float4 hv = h4[j];
                acc += hv.x * wcol[j * 4]     + hv.y * wcol[j * 4 + 1]
                     + hv.z * wcol[j * 4 + 2] + hv.w * wcol[j * 4 + 3];
            }
            out[(size_t)i * 32 + f] = fmaxf(acc, 0.0f) * dinv[i];
        }
    }
}

// ---- mm3: h3 = relu(a2 @ W3 + b3), K=32 F=64 (R7)
__global__ void k_mm3(const float* __restrict__ H, const float* __restrict__ W,
                      const float* __restrict__ b, float* __restrict__ out,
                      int n, int nwaves) {
    int lane = threadIdx.x & 63;
    int wid = (blockIdx.x * blockDim.x + threadIdx.x) >> 6;
    float wcol[32];
    #pragma unroll
    for (int k = 0; k < 32; ++k) wcol[k] = W[k * 64 + lane];
    float bias = b[lane];
    for (int i = wid; i < n; i += nwaves) {
        const float4* h4 = (const float4*)(H + (size_t)i * 32);
        float acc = bias;
        #pragma unroll
        for (int j = 0; j < 8; ++j) {
            float4 hv = h4[j];
            acc += hv.x * wcol[j * 4]     + hv.y * wcol[j * 4 + 1]
                 + hv.z * wcol[j * 4 + 2] + hv.w * wcol[j * 4 + 3];
        }
        out[(size_t)i * 64 + lane] = fmaxf(acc, 0.0f);
    }
}

// ---- fused mean-pool + MLP head: one block (64 threads) per graph.
__global__ void k_poolhead(const float* __restrict__ h3, const int* __restrict__ batch,
                           const float* __restrict__ Wl1, const float* __restrict__ bl1,
                           const float* __restrict__ Wl2, const float* __restrict__ bl2,
                           float* __restrict__ out, int n) {
    int g = blockIdx.x, t = threadIdx.x;
    __shared__ int sb[2];
    __shared__ float mean[64], hid[64];
    if (t < 2) {
        int target = g + t;
        int lo = 0, hi = n;
        while (lo < hi) {
            int mid = (lo + hi) >> 1;
            if (batch[mid] < target) lo = mid + 1; else hi = mid;
        }
        sb[t] = lo;
    }
    __syncthreads();
    int s = sb[0], e = sb[1];
    float acc = 0.0f;
    for (int i = s; i < e; ++i) acc += h3[(size_t)i * 64 + t];
    float c = fmaxf((float)(e - s), 1.0f);
    mean[t] = acc / c;
    __syncthreads();
    float a = bl1[t];
    #pragma unroll 8
    for (int k = 0; k < 64; ++k) a += mean[k] * Wl1[k * 64 + t];
    hid[t] = fmaxf(a, 0.0f);
    __syncthreads();
    if (t < 2) {
        float o = bl2[t];
        #pragma unroll 8
        for (int k = 0; k < 64; ++k) o += hid[k] * Wl2[k * 2 + t];
        out[g * 2 + t] = o;
    }
}

extern "C" void kernel_launch(void* const* d_in, const int* in_sizes, int n_in,
                              void* d_out, int out_size, void* d_ws, size_t ws_size,
                              hipStream_t stream) {
    const float* x    = (const float*)d_in[0];
    const int*   ei   = (const int*)d_in[1];
    const int*   batch= (const int*)d_in[2];
    const float* W1   = (const float*)d_in[3];
    const float* b1   = (const float*)d_in[4];
    const float* W2   = (const float*)d_in[5];
    const float* b2   = (const float*)d_in[6];
    const float* W3   = (const float*)d_in[7];
    const float* b3   = (const float*)d_in[8];
    const float* Wl1  = (const float*)d_in[9];
    const float* bl1  = (const float*)d_in[10];
    const float* Wl2  = (const float*)d_in[11];
    const float* bl2  = (const float*)d_in[12];
    float* out = (float*)d_out;

    const int n  = in_sizes[2];      // 100000
    const int nE = in_sizes[1] / 2;  // 3200000
    const int* src = ei;
    const int* dst = ei + nE;

    const int NBKT  = (n + 255) >> 8;        // 391 buckets (256 nodes each)
    const int NBLKA = (nE + EPA - 1) / EPA;  // 391 scatA blocks
    const int NG    = 1024;
    const int qsz   = (n + 3) / 4;           // src-quartile size

    char* w = (char*)d_ws;
    auto alloc_f = [&](size_t cnt) { float* p = (float*)w; w += cnt * 4; return p; };
    auto alloc_i = [&](size_t cnt) { int*   p = (int*)w;   w += cnt * 4; return p; };

    float*    dinv   = alloc_f(n);
    int*      start  = alloc_i(n);
    unsigned* poff   = (unsigned*)alloc_i(n);
    int*      cntT   = alloc_i((size_t)NBLKA * MAXBKT);
    int*      po2T   = alloc_i((size_t)NBLKA * MAXBKT);
    int*      totals = alloc_i(MAXBKT);
    int*      bstart = alloc_i(MAXBKT + 1);
    unsigned* ebuf   = (unsigned*)alloc_i(nE);   // 12.8 MB
    int*      col    = alloc_i(nE);              // 12.8 MB (contiguous after ebuf)
    float* Pd1 = alloc_f((size_t)n * 16);
    float* h1d = alloc_f((size_t)n * 16);
    float* a1  = alloc_f((size_t)n * 16);
    float* h2d = alloc_f((size_t)n * 32);
    float* a2  = Pd1;            // 32n over Pd1+h1d (both dead by agg3)
    float* h3  = (float*)ebuf;   // 64n over ebuf+col (dead by mm3)

    const int B = 256;
    auto g = [&](long long t) { return (int)((t + B - 1) / B); };
    const int MMBLK = 1024;
    const int NW = MMBLK * (B / 64);

    // ---- CSR build: block-local sort -> slabs; bucket gather-sort -> CSR
    k_scatA<<<NBLKA, 512, 0, stream>>>(src, dst, cntT, po2T, ebuf, nE);
    k_totals<<<NBKT, 256, 0, stream>>>(cntT, totals, NBLKA);
    k_scanB<<<1, MAXBKT, 0, stream>>>(totals, bstart, NBKT, nE);
    k_bsort<<<NBKT, 512, 0, stream>>>(ebuf, cntT, po2T, bstart, col, start, dinv,
                                      poff, n, qsz, NBLKA);

    // ---- layer 1: Pd1 = dinv*(x@W1); h1d = dinv*relu(dinv*Agg(Pd1)+b1)
    k_mm1<<<(n + 63) / 64, 256, 0, stream>>>((const float4*)x, (const float4*)W1,
                                             dinv, Pd1, n);
    k_agg<16, 0, 2, 1><<<g((long long)n * 4), B, 0, stream>>>(Pd1, start, poff, col, dinv, b1, h1d, n);
    k_agg<16, 2, 4, 1><<<g((long long)n * 4), B, 0, stream>>>(Pd1, start, poff, col, dinv, b1, h1d, n);

    // ---- layer 2: a1 = dinv*Agg(h1d); h2d = dinv*relu(a1@W2+b2)
    k_agg<16, 0, 2, 0><<<g((long long)n * 4), B, 0, stream>>>(h1d, start, poff, col, dinv, nullptr, a1, n);
    k_agg<16, 2, 4, 0><<<g((long long)n * 4), B, 0, stream>>>(h1d, start, poff, col, dinv, nullptr, a1, n);
    k_mm2<<<MMBLK, B, 0, stream>>>(a1, W2, b2, dinv, h2d, n, NW);

    // ---- layer 3: a2 = dinv*Agg(h2d); h3 = relu(a2@W3+b3)
    k_agg<32, 0, 1, 0><<<g((long long)n * 8), B, 0, stream>>>(h2d, start, poff, col, dinv, nullptr, a2, n);
    k_agg<32, 1, 2, 0><<<g((long long)n * 8), B, 0, stream>>>(h2d, start, poff, col, dinv, nullptr, a2, n);
    k_agg<32, 2, 3, 0><<<g((long long)n * 8), B, 0, stream>>>(h2d, start, poff, col, dinv, nullptr, a2, n);
    k_agg<32, 3, 4, 0><<<g((long long)n * 8), B, 0, stream>>>(h2d, start, poff, col, dinv, nullptr, a2, n);
    k_mm3<<<MMBLK, B, 0, stream>>>(a2, W3, b3, h3, n, NW);

    // ---- fused mean-pool + head (no atomics; batch is sorted)
    k_poolhead<<<NG, 64, 0, stream>>>(h3, batch, Wl1, bl1, Wl2, bl2, out, n);
}

// Round 9
// 330.709 us; speedup vs baseline: 2.3488x; 1.0479x over previous
//
#include <hip/hip_runtime.h>

// GCN forward: 3x GCNConv (symmetric norm, self-loops) + mean-pool + MLP head.
// R9: 128-node buckets, stash-free bsort (2 direct L2-hot passes), transposed
//     CSR-build metadata (contiguous bsort reads), 1024-thread scatA,
//     256-thread poolhead. (R8: bsort grid/LDS-limited at 24% occ, 19.6MB of
//     its 20.6MB FETCH was strided metadata.)

constexpr int EPA  = 8192;   // edges per scatA block
constexpr int NPB  = 128;    // nodes per bucket
constexpr int PADB = 784;    // cntT row stride  ([block][bucket])
constexpr int PADA = 400;    // cntTT row stride ([bucket][block])

// ---- scatA: per-block histogram + local counting sort -> contiguous slab.
__global__ __launch_bounds__(1024) void k_scatA(const int* __restrict__ src,
        const int* __restrict__ dst, int* __restrict__ cntT, int* __restrict__ po2T,
        unsigned* __restrict__ ebuf, int nE, int NBKT) {
    __shared__ int hist[1024], scan[1024], lcur[800];
    int blk = blockIdx.x, t = threadIdx.x;
    hist[t] = 0;
    __syncthreads();
    int base = blk * EPA, end = min(base + EPA, nE);
    for (int e = base + t; e < end; e += 1024)
        atomicAdd(&hist[dst[e] >> 7], 1);  // LDS
    __syncthreads();
    int v = hist[t];
    scan[t] = v;
    __syncthreads();
    for (int off = 1; off < 1024; off <<= 1) {
        int u = (t >= off) ? scan[t - off] : 0;
        __syncthreads();
        scan[t] += u;
        __syncthreads();
    }
    int ex = scan[t] - v;  // exclusive local offset
    if (t < NBKT) {
        lcur[t] = ex;
        cntT[blk * PADB + t] = v;   // coalesced
        po2T[blk * PADB + t] = ex;  // coalesced
    }
    __syncthreads();
    for (int e = base + t; e < end; e += 1024) {
        int s = src[e], d = dst[e];             // L2-hot re-read
        int pos = atomicAdd(&lcur[d >> 7], 1);  // LDS
        ebuf[base + pos] = ((unsigned)(d & 127) << 17) | (unsigned)s;  // 32KB window
    }
}

// ---- tiled transpose of cntT/po2T into [bucket][block]; fused bucket totals.
__global__ __launch_bounds__(256) void k_transpose(const int* __restrict__ cntT,
        const int* __restrict__ po2T, int* __restrict__ cntTT, int* __restrict__ po2TT,
        int* __restrict__ totals, int NBLKA, int NBKT) {
    __shared__ int tile[64][65];
    int bktTile = blockIdx.x * 64, blkTile = blockIdx.y * 64;
    int c = threadIdx.x & 63, r4 = threadIdx.x >> 6;
    // --- cnt
    for (int rr = r4; rr < 64; rr += 4) {
        int blk = blkTile + rr, bkt = bktTile + c;
        tile[rr][c] = (blk < NBLKA && bkt < NBKT) ? cntT[blk * PADB + bkt] : 0;
    }
    __syncthreads();
    for (int rr = r4; rr < 64; rr += 4) {
        int bkt = bktTile + rr, blk = blkTile + c;
        if (bkt < NBKT && blk < NBLKA) cntTT[bkt * PADA + blk] = tile[c][rr];
        // partial bucket totals: wave r4 reduces row rr over lanes (c)
        int val = tile[c][rr];
        #pragma unroll
        for (int o = 32; o > 0; o >>= 1) val += __shfl_xor(val, o);
        if (c == 0 && bkt < NBKT && val != 0) atomicAdd(&totals[bkt], val);
    }
    __syncthreads();
    // --- po2
    for (int rr = r4; rr < 64; rr += 4) {
        int blk = blkTile + rr, bkt = bktTile + c;
        tile[rr][c] = (blk < NBLKA && bkt < NBKT) ? po2T[blk * PADB + bkt] : 0;
    }
    __syncthreads();
    for (int rr = r4; rr < 64; rr += 4) {
        int bkt = bktTile + rr, blk = blkTile + c;
        if (bkt < NBKT && blk < NBLKA) po2TT[bkt * PADA + blk] = tile[c][rr];
    }
}

// ---- exclusive scan of bucket totals -> global CSR bucket bases
__global__ __launch_bounds__(1024) void k_scanB(const int* __restrict__ totals,
        int* __restrict__ bstart, int NBKT, int nE) {
    __shared__ int sc[1024];
    int t = threadIdx.x;
    int v = (t < NBKT) ? totals[t] : 0;
    sc[t] = v;
    __syncthreads();
    for (int off = 1; off < 1024; off <<= 1) {
        int u = (t >= off) ? sc[t - off] : 0;
        __syncthreads();
        sc[t] += u;
        __syncthreads();
    }
    if (t < NBKT) bstart[t] = sc[t] - v;
    if (t == 0) bstart[NBKT] = nE;
}

// ---- bsort: two direct passes over this bucket's (L2-hot) slab segments;
//      counting sort by (node, src-quartile) -> CSR col.
__global__ __launch_bounds__(512) void k_bsort(const unsigned* __restrict__ ebuf,
        const int* __restrict__ cntTT, const int* __restrict__ po2TT,
        const int* __restrict__ bstart, int* __restrict__ col, int* __restrict__ start,
        float* __restrict__ dinv, unsigned* __restrict__ poff,
        int n, int qsz, int NBLKA) {
    __shared__ int slen[400], soff[400];
    __shared__ int hist4[512], cur4[512], excl[128];
    int b = blockIdx.x, t = threadIdx.x;
    if (t < NBLKA) {
        slen[t] = cntTT[b * PADA + t];              // contiguous
        soff[t] = t * EPA + po2TT[b * PADA + t];    // contiguous
    }
    hist4[t] = 0;
    __syncthreads();
    int wv = t >> 6, lane = t & 63;
    for (int s = wv; s < NBLKA; s += 8) {
        int sl = slen[s], so = soff[s];
        for (int j = lane; j < sl; j += 64) {
            unsigned u = ebuf[so + j];
            atomicAdd(&hist4[(u >> 17) * 4 + (int)(u & 0x1FFFFu) / qsz], 1);  // LDS
        }
    }
    __syncthreads();
    int c0 = 0, c1 = 0, c2 = 0, c3 = 0, v = 0;
    if (t < 128) {
        c0 = hist4[t * 4];     c1 = hist4[t * 4 + 1];
        c2 = hist4[t * 4 + 2]; c3 = hist4[t * 4 + 3];
        v = c0 + c1 + c2 + c3;
        excl[t] = v;
    }
    __syncthreads();
    for (int off = 1; off < 128; off <<= 1) {
        int u = (t >= off && t < 128) ? excl[t - off] : 0;
        __syncthreads();
        if (t < 128) excl[t] += u;
        __syncthreads();
    }
    if (t < 128) {
        int sbase = bstart[b] + excl[t] - v;
        cur4[t * 4]     = sbase;
        cur4[t * 4 + 1] = sbase + c0;
        cur4[t * 4 + 2] = sbase + c0 + c1;
        cur4[t * 4 + 3] = sbase + c0 + c1 + c2;
        int node = (b << 7) + t;
        if (node < n) {
            start[node] = sbase;
            dinv[node] = rsqrtf((float)(v + 1));
            poff[node] = (unsigned)c0 | ((unsigned)c1 << 8) |
                         ((unsigned)c2 << 16) | ((unsigned)c3 << 24);
        }
    }
    __syncthreads();
    for (int s = wv; s < NBLKA; s += 8) {
        int sl = slen[s], so = soff[s];
        for (int j = lane; j < sl; j += 64) {
            unsigned u = ebuf[so + j];  // L2-hot (read in pass 1)
            int pos = atomicAdd(&cur4[(u >> 17) * 4 + (int)(u & 0x1FFFFu) / qsz], 1);
            col[pos] = (int)(u & 0x1FFFFu);  // ~16KB window
        }
    }
}

// ---- multi-pass aggregation over dinv-prescaled rows T (unchanged)
template <int F, int P0, int P1, int EPI>
__global__ void k_agg(const float* __restrict__ T, const int* __restrict__ start,
                      const unsigned* __restrict__ poff, const int* __restrict__ col,
                      const float* __restrict__ dinv, const float* __restrict__ bias,
                      float* __restrict__ out, int n) {
    constexpr int TPN = F / 4;
    constexpr bool FIRST = (P0 == 0), LAST = (P1 == 4);
    int idx = blockIdx.x * blockDim.x + threadIdx.x;
    int i = idx / TPN;
    int q = idx % TPN;
    if (i >= n) return;
    unsigned pk = poff[i];
    int cs[4] = {(int)(pk & 255u), (int)((pk >> 8) & 255u),
                 (int)((pk >> 16) & 255u), (int)(pk >> 24)};
    int off = 0;
    #pragma unroll
    for (int p = 0; p < P0; ++p) off += cs[p];
    int len = 0;
    #pragma unroll
    for (int p = P0; p < P1; ++p) len += cs[p];
    int base = start[i] + off;
    const float4* T4 = (const float4*)T;
    float4* O4 = (float4*)out;
    float4 acc = FIRST ? T4[(size_t)i * TPN + q] : O4[(size_t)i * TPN + q];
    int k = 0;
    for (; k + 4 <= len; k += 4) {
        int s0 = col[base + k],     s1 = col[base + k + 1];
        int s2 = col[base + k + 2], s3 = col[base + k + 3];
        float4 v0 = T4[(size_t)s0 * TPN + q];
        float4 v1 = T4[(size_t)s1 * TPN + q];
        float4 v2 = T4[(size_t)s2 * TPN + q];
        float4 v3 = T4[(size_t)s3 * TPN + q];
        acc.x += v0.x + v1.x + v2.x + v3.x;
        acc.y += v0.y + v1.y + v2.y + v3.y;
        acc.z += v0.z + v1.z + v2.z + v3.z;
        acc.w += v0.w + v1.w + v2.w + v3.w;
    }
    for (; k < len; ++k) {
        float4 v = T4[(size_t)col[base + k] * TPN + q];
        acc.x += v.x; acc.y += v.y; acc.z += v.z; acc.w += v.w;
    }
    if (LAST) {
        float d = dinv[i];
        float4 o;
        if (EPI == 0) {
            o.x = d * acc.x; o.y = d * acc.y; o.z = d * acc.z; o.w = d * acc.w;
        } else {
            float4 b = ((const float4*)bias)[q];
            o.x = d * fmaxf(d * acc.x + b.x, 0.0f);
            o.y = d * fmaxf(d * acc.y + b.y, 0.0f);
            o.z = d * fmaxf(d * acc.z + b.z, 0.0f);
            o.w = d * fmaxf(d * acc.w + b.w, 0.0f);
        }
        O4[(size_t)i * TPN + q] = o;
    } else {
        O4[(size_t)i * TPN + q] = acc;
    }
}

// ---- mm1: Pd1 = dinv * (x @ W1), K=128 F=16. LDS-tiled (R8).
__global__ __launch_bounds__(256) void k_mm1(const float4* __restrict__ X4,
        const float4* __restrict__ W4, const float* __restrict__ dinv,
        float* __restrict__ out, int n) {
    __shared__ float4 xs[64 * 32];
    __shared__ float4 ws[512];
    int t = threadIdx.x;
    int nb = blockIdx.x * 64;
    ws[t] = W4[t]; ws[t + 256] = W4[t + 256];
    int lim = min(64, n - nb);
    #pragma unroll
    for (int it = 0; it < 8; ++it) {
        int idx = it * 256 + t;
        if ((idx >> 5) < lim) xs[idx] = X4[(size_t)nb * 32 + idx];
    }
    __syncthreads();
    int lane = t & 63, wv = t >> 6;
    int f = lane & 15, kc = lane >> 4;
    float wcol[32];
    #pragma unroll
    for (int kk = 0; kk < 32; ++kk)
        wcol[kk] = ((const float*)ws)[(kc * 32 + kk) * 16 + f];
    for (int ln = wv * 16; ln < wv * 16 + 16; ++ln) {
        if (ln >= lim) break;
        int i = nb + ln;
        float acc = 0.0f;
        #pragma unroll
        for (int j = 0; j < 8; ++j) {
            float4 hv = xs[ln * 32 + kc * 8 + j];
            acc += hv.x * wcol[4 * j]     + hv.y * wcol[4 * j + 1]
                 + hv.z * wcol[4 * j + 2] + hv.w * wcol[4 * j + 3];
        }
        acc += __shfl_xor(acc, 16);
        acc += __shfl_xor(acc, 32);
        if (kc == 0) out[(size_t)i * 16 + f] = acc * dinv[i];
    }
}

// ---- mm2: h2d = dinv * relu(a1 @ W2 + b2), K=16 F=32
__global__ void k_mm2(const float* __restrict__ H, const float* __restrict__ W,
                      const float* __restrict__ b, const float* __restrict__ dinv,
                      float* __restrict__ out, int n, int nwaves) {
    int lane = threadIdx.x & 63;
    int wid = (blockIdx.x * blockDim.x + threadIdx.x) >> 6;
    int f = lane & 31, p = lane >> 5;
    float wcol[16];
    #pragma unroll
    for (int k = 0; k < 16; ++k) wcol[k] = W[k * 32 + f];
    float bias = b[f];
    for (int i0 = wid * 2; i0 < n; i0 += nwaves * 2) {
        int i = i0 + p;
        if (i < n) {
            const float4* h4 = (const float4*)(H + (size_t)i * 16);
            float acc = bias;
            #pragma unroll
            for (int j = 0; j < 4; ++j) {
                float4 hv = h4[j];
                acc += hv.x * wcol[j * 4]     + hv.y * wcol[j * 4 + 1]
                     + hv.z * wcol[j * 4 + 2] + hv.w * wcol[j * 4 + 3];
            }
            out[(size_t)i * 32 + f] = fmaxf(acc, 0.0f) * dinv[i];
        }
    }
}

// ---- mm3: h3 = relu(a2 @ W3 + b3), K=32 F=64
__global__ void k_mm3(const float* __restrict__ H, const float* __restrict__ W,
                      const float* __restrict__ b, float* __restrict__ out,
                      int n, int nwaves) {
    int lane = threadIdx.x & 63;
    int wid = (blockIdx.x * blockDim.x + threadIdx.x) >> 6;
    float wcol[32];
    #pragma unroll
    for (int k = 0; k < 32; ++k) wcol[k] = W[k * 64 + lane];
    float bias = b[lane];
    for (int i = wid; i < n; i += nwaves) {
        const float4* h4 = (const float4*)(H + (size_t)i * 32);
        float acc = bias;
        #pragma unroll
        for (int j = 0; j < 8; ++j) {
            float4 hv = h4[j];
            acc += hv.x * wcol[j * 4]     + hv.y * wcol[j * 4 + 1]
                 + hv.z * wcol[j * 4 + 2] + hv.w * wcol[j * 4 + 3];
        }
        out[(size_t)i * 64 + lane] = fmaxf(acc, 0.0f);
    }
}

// ---- fused mean-pool + MLP head: 256 threads per graph (4-way row parallel)
__global__ __launch_bounds__(256) void k_poolhead(const float* __restrict__ h3,
        const int* __restrict__ batch, const float* __restrict__ Wl1,
        const float* __restrict__ bl1, const float* __restrict__ Wl2,
        const float* __restrict__ bl2, float* __restrict__ out, int n) {
    int g = blockIdx.x, t = threadIdx.x;
    int f = t & 63, r = t >> 6;
    __shared__ int sb[2];
    __shared__ float part[4][64];
    __shared__ float mean[64], hid[64];
    if (t < 2) {
        int target = g + t;
        int lo = 0, hi = n;
        while (lo < hi) {
            int mid = (lo + hi) >> 1;
            if (batch[mid] < target) lo = mid + 1; else hi = mid;
        }
        sb[t] = lo;
    }
    __syncthreads();
    int s = sb[0], e = sb[1];
    float acc = 0.0f;
    for (int i = s + r; i < e; i += 4) acc += h3[(size_t)i * 64 + f];
    part[r][f] = acc;
    __syncthreads();
    if (t < 64) {
        float c = fmaxf((float)(e - s), 1.0f);
        mean[t] = (part[0][t] + part[1][t] + part[2][t] + part[3][t]) / c;
    }
    __syncthreads();
    if (t < 64) {
        float a = bl1[t];
        #pragma unroll 8
        for (int k = 0; k < 64; ++k) a += mean[k] * Wl1[k * 64 + t];
        hid[t] = fmaxf(a, 0.0f);
    }
    __syncthreads();
    if (t < 2) {
        float o = bl2[t];
        #pragma unroll 8
        for (int k = 0; k < 64; ++k) o += hid[k] * Wl2[k * 2 + t];
        out[g * 2 + t] = o;
    }
}

extern "C" void kernel_launch(void* const* d_in, const int* in_sizes, int n_in,
                              void* d_out, int out_size, void* d_ws, size_t ws_size,
                              hipStream_t stream) {
    const float* x    = (const float*)d_in[0];
    const int*   ei   = (const int*)d_in[1];
    const int*   batch= (const int*)d_in[2];
    const float* W1   = (const float*)d_in[3];
    const float* b1   = (const float*)d_in[4];
    const float* W2   = (const float*)d_in[5];
    const float* b2   = (const float*)d_in[6];
    const float* W3   = (const float*)d_in[7];
    const float* b3   = (const float*)d_in[8];
    const float* Wl1  = (const float*)d_in[9];
    const float* bl1  = (const float*)d_in[10];
    const float* Wl2  = (const float*)d_in[11];
    const float* bl2  = (const float*)d_in[12];
    float* out = (float*)d_out;

    const int n  = in_sizes[2];      // 100000
    const int nE = in_sizes[1] / 2;  // 3200000
    const int* src = ei;
    const int* dst = ei + nE;

    const int NBKT  = (n + NPB - 1) / NPB;   // 782 buckets (128 nodes each)
    const int NBLKA = (nE + EPA - 1) / EPA;  // 391 scatA blocks
    const int NG    = 1024;
    const int qsz   = (n + 3) / 4;           // src-quartile size

    char* w = (char*)d_ws;
    auto alloc_f = [&](size_t cnt) { float* p = (float*)w; w += cnt * 4; return p; };
    auto alloc_i = [&](size_t cnt) { int*   p = (int*)w;   w += cnt * 4; return p; };

    float*    dinv   = alloc_f(n);
    int*      start  = alloc_i(n);
    unsigned* poff   = (unsigned*)alloc_i(n);
    int*      cntT   = alloc_i((size_t)NBLKA * PADB);
    int*      po2T   = alloc_i((size_t)NBLKA * PADB);
    int*      cntTT  = alloc_i((size_t)NBKT * PADA);
    int*      po2TT  = alloc_i((size_t)NBKT * PADA);
    int*      totals = alloc_i(1024);
    int*      bstart = alloc_i(1024);
    unsigned* ebuf   = (unsigned*)alloc_i(nE);   // 12.8 MB
    int*      col    = alloc_i(nE);              // 12.8 MB (contiguous after ebuf)
    float* Pd1 = alloc_f((size_t)n * 16);
    float* h1d = alloc_f((size_t)n * 16);
    float* a1  = alloc_f((size_t)n * 16);
    float* h2d = alloc_f((size_t)n * 32);
    float* a2  = Pd1;            // 32n over Pd1+h1d (both dead by agg3)
    float* h3  = (float*)ebuf;   // 64n over ebuf+col (dead by mm3)

    const int B = 256;
    auto g = [&](long long t) { return (int)((t + B - 1) / B); };
    const int MMBLK = 1024;
    const int NW = MMBLK * (B / 64);

    // ---- CSR build
    hipMemsetAsync(totals, 0, 1024 * sizeof(int), stream);
    k_scatA<<<NBLKA, 1024, 0, stream>>>(src, dst, cntT, po2T, ebuf, nE, NBKT);
    k_transpose<<<dim3((NBKT + 63) / 64, (NBLKA + 63) / 64), 256, 0, stream>>>(
        cntT, po2T, cntTT, po2TT, totals, NBLKA, NBKT);
    k_scanB<<<1, 1024, 0, stream>>>(totals, bstart, NBKT, nE);
    k_bsort<<<NBKT, 512, 0, stream>>>(ebuf, cntTT, po2TT, bstart, col, start, dinv,
                                      poff, n, qsz, NBLKA);

    // ---- layer 1: Pd1 = dinv*(x@W1); h1d = dinv*relu(dinv*Agg(Pd1)+b1)
    k_mm1<<<(n + 63) / 64, 256, 0, stream>>>((const float4*)x, (const float4*)W1,
                                             dinv, Pd1, n);
    k_agg<16, 0, 2, 1><<<g((long long)n * 4), B, 0, stream>>>(Pd1, start, poff, col, dinv, b1, h1d, n);
    k_agg<16, 2, 4, 1><<<g((long long)n * 4), B, 0, stream>>>(Pd1, start, poff, col, dinv, b1, h1d, n);

    // ---- layer 2: a1 = dinv*Agg(h1d); h2d = dinv*relu(a1@W2+b2)
    k_agg<16, 0, 2, 0><<<g((long long)n * 4), B, 0, stream>>>(h1d, start, poff, col, dinv, nullptr, a1, n);
    k_agg<16, 2, 4, 0><<<g((long long)n * 4), B, 0, stream>>>(h1d, start, poff, col, dinv, nullptr, a1, n);
    k_mm2<<<MMBLK, B, 0, stream>>>(a1, W2, b2, dinv, h2d, n, NW);

    // ---- layer 3: a2 = dinv*Agg(h2d); h3 = relu(a2@W3+b3)
    k_agg<32, 0, 1, 0><<<g((long long)n * 8), B, 0, stream>>>(h2d, start, poff, col, dinv, nullptr, a2, n);
    k_agg<32, 1, 2, 0><<<g((long long)n * 8), B, 0, stream>>>(h2d, start, poff, col, dinv, nullptr, a2, n);
    k_agg<32, 2, 3, 0><<<g((long long)n * 8), B, 0, stream>>>(h2d, start, poff, col, dinv, nullptr, a2, n);
    k_agg<32, 3, 4, 0><<<g((long long)n * 8), B, 0, stream>>>(h2d, start, poff, col, dinv, nullptr, a2, n);
    k_mm3<<<MMBLK, B, 0, stream>>>(a2, W3, b3, h3, n, NW);

    // ---- fused mean-pool + head (no atomics; batch is sorted)
    k_poolhead<<<NG, 256, 0, stream>>>(h3, batch, Wl1, bl1, Wl2, bl2, out, n);
}

// Round 10
// 290.249 us; speedup vs baseline: 2.6762x; 1.1394x over previous
//
#include <hip/hip_runtime.h>

// GCN forward: 3x GCNConv (symmetric norm, self-loops) + mean-pool + MLP head.
// R10: two-level radix CSR build. Level 1: 196 super-buckets x 512 nodes
//      (big segments, ~1.1x write amp). Level 2: per-sb contiguous stream +
//      LDS counting sort. (R9 bsort read 391 x ~42B fragments/bucket = 50MB
//      FETCH at 16% lane utilization.)

constexpr int EPA1 = 16384;  // edges per level-1 block
constexpr int NPSB = 512;    // nodes per super-bucket
constexpr int PAD1 = 200;    // [blk][sb] metadata row stride

// ---- level 1 histogram: per-block super-bucket counts
__global__ __launch_bounds__(1024) void k_hist1(const int* __restrict__ dst,
        int* __restrict__ cnt1, int nE, int NSB) {
    __shared__ int hist[256];
    int t = threadIdx.x;
    if (t < 256) hist[t] = 0;
    __syncthreads();
    int base = blockIdx.x * EPA1, end = min(base + EPA1, nE);
    for (int e = base + t; e < end; e += 1024)
        atomicAdd(&hist[dst[e] >> 9], 1);  // LDS
    __syncthreads();
    if (t < NSB) cnt1[blockIdx.x * PAD1 + t] = hist[t];
}

// ---- level 1 scan: per-sb exclusive prefix over blocks (metadata is tiny/L2)
__global__ __launch_bounds__(256) void k_scan1(const int* __restrict__ cnt1,
        int* __restrict__ po1, int* __restrict__ totals, int NBLK1) {
    __shared__ int sc[256];
    int sb = blockIdx.x, t = threadIdx.x;
    int v = (t < NBLK1) ? cnt1[t * PAD1 + sb] : 0;
    sc[t] = v;
    __syncthreads();
    for (int off = 1; off < 256; off <<= 1) {
        int u = (t >= off) ? sc[t - off] : 0;
        __syncthreads();
        sc[t] += u;
        __syncthreads();
    }
    if (t < NBLK1) po1[t * PAD1 + sb] = sc[t] - v;
    if (t == 255) totals[sb] = sc[255];
}

// ---- exclusive scan of super-bucket totals
__global__ __launch_bounds__(256) void k_scanB(const int* __restrict__ totals,
        int* __restrict__ sbstart, int NSB, int nE) {
    __shared__ int sc[256];
    int t = threadIdx.x;
    int v = (t < NSB) ? totals[t] : 0;
    sc[t] = v;
    __syncthreads();
    for (int off = 1; off < 256; off <<= 1) {
        int u = (t >= off) ? sc[t - off] : 0;
        __syncthreads();
        sc[t] += u;
        __syncthreads();
    }
    if (t < NSB) sbstart[t] = sc[t] - v;
    if (t == 0) sbstart[NSB] = nE;
}

// ---- level 1 scatter: edges -> super-bucket-major ebuf (packed lnode|src)
__global__ __launch_bounds__(1024) void k_scat1(const int* __restrict__ src,
        const int* __restrict__ dst, const int* __restrict__ po1,
        const int* __restrict__ sbstart, unsigned* __restrict__ ebuf,
        int nE, int NSB) {
    __shared__ int cur[256];
    int t = threadIdx.x, blk = blockIdx.x;
    if (t < NSB) cur[t] = sbstart[t] + po1[blk * PAD1 + t];
    __syncthreads();
    int base = blk * EPA1, end = min(base + EPA1, nE);
    for (int e = base + t; e < end; e += 1024) {
        int s = src[e], d = dst[e];
        int pos = atomicAdd(&cur[d >> 9], 1);  // LDS
        ebuf[pos] = ((unsigned)(d & 511) << 17) | (unsigned)s;  // ~334B segments
    }
}

// ---- level 2: per-sb contiguous counting sort by (node, src-quartile)
__global__ __launch_bounds__(512) void k_sort2(const unsigned* __restrict__ ebuf,
        const int* __restrict__ sbstart, int* __restrict__ col,
        int* __restrict__ start, float* __restrict__ dinv,
        unsigned* __restrict__ poff, int n, int qsz) {
    __shared__ int hist4[2048], cur4[2048], excl[512];
    int b = blockIdx.x, t = threadIdx.x;
    int ebase = sbstart[b], eend = sbstart[b + 1];
    hist4[t] = 0; hist4[t + 512] = 0; hist4[t + 1024] = 0; hist4[t + 1536] = 0;
    __syncthreads();
    for (int e = ebase + t; e < eend; e += 512) {
        unsigned u = ebuf[e];  // contiguous stream
        atomicAdd(&hist4[(u >> 17) * 4 + (int)(u & 0x1FFFFu) / qsz], 1);  // LDS
    }
    __syncthreads();
    int c0 = hist4[t * 4],     c1 = hist4[t * 4 + 1];
    int c2 = hist4[t * 4 + 2], c3 = hist4[t * 4 + 3];
    int v = c0 + c1 + c2 + c3;
    excl[t] = v;
    __syncthreads();
    for (int off = 1; off < 512; off <<= 1) {
        int u = (t >= off) ? excl[t - off] : 0;
        __syncthreads();
        excl[t] += u;
        __syncthreads();
    }
    int sbase = ebase + excl[t] - v;
    cur4[t * 4]     = sbase;
    cur4[t * 4 + 1] = sbase + c0;
    cur4[t * 4 + 2] = sbase + c0 + c1;
    cur4[t * 4 + 3] = sbase + c0 + c1 + c2;
    int node = (b << 9) + t;
    if (node < n) {
        start[node] = sbase;
        dinv[node] = rsqrtf((float)(v + 1));
        poff[node] = (unsigned)c0 | ((unsigned)c1 << 8) |
                     ((unsigned)c2 << 16) | ((unsigned)c3 << 24);
    }
    __syncthreads();
    for (int e = ebase + t; e < eend; e += 512) {
        unsigned u = ebuf[e];  // L2-hot (read in pass 1)
        int s = (int)(u & 0x1FFFFu);
        int pos = atomicAdd(&cur4[(u >> 17) * 4 + s / qsz], 1);  // LDS
        col[pos] = s;  // ~65KB window
    }
}

// ---- multi-pass aggregation over dinv-prescaled rows T (unchanged)
template <int F, int P0, int P1, int EPI>
__global__ void k_agg(const float* __restrict__ T, const int* __restrict__ start,
                      const unsigned* __restrict__ poff, const int* __restrict__ col,
                      const float* __restrict__ dinv, const float* __restrict__ bias,
                      float* __restrict__ out, int n) {
    constexpr int TPN = F / 4;
    constexpr bool FIRST = (P0 == 0), LAST = (P1 == 4);
    int idx = blockIdx.x * blockDim.x + threadIdx.x;
    int i = idx / TPN;
    int q = idx % TPN;
    if (i >= n) return;
    unsigned pk = poff[i];
    int cs[4] = {(int)(pk & 255u), (int)((pk >> 8) & 255u),
                 (int)((pk >> 16) & 255u), (int)(pk >> 24)};
    int off = 0;
    #pragma unroll
    for (int p = 0; p < P0; ++p) off += cs[p];
    int len = 0;
    #pragma unroll
    for (int p = P0; p < P1; ++p) len += cs[p];
    int base = start[i] + off;
    const float4* T4 = (const float4*)T;
    float4* O4 = (float4*)out;
    float4 acc = FIRST ? T4[(size_t)i * TPN + q] : O4[(size_t)i * TPN + q];
    int k = 0;
    for (; k + 4 <= len; k += 4) {
        int s0 = col[base + k],     s1 = col[base + k + 1];
        int s2 = col[base + k + 2], s3 = col[base + k + 3];
        float4 v0 = T4[(size_t)s0 * TPN + q];
        float4 v1 = T4[(size_t)s1 * TPN + q];
        float4 v2 = T4[(size_t)s2 * TPN + q];
        float4 v3 = T4[(size_t)s3 * TPN + q];
        acc.x += v0.x + v1.x + v2.x + v3.x;
        acc.y += v0.y + v1.y + v2.y + v3.y;
        acc.z += v0.z + v1.z + v2.z + v3.z;
        acc.w += v0.w + v1.w + v2.w + v3.w;
    }
    for (; k < len; ++k) {
        float4 v = T4[(size_t)col[base + k] * TPN + q];
        acc.x += v.x; acc.y += v.y; acc.z += v.z; acc.w += v.w;
    }
    if (LAST) {
        float d = dinv[i];
        float4 o;
        if (EPI == 0) {
            o.x = d * acc.x; o.y = d * acc.y; o.z = d * acc.z; o.w = d * acc.w;
        } else {
            float4 b = ((const float4*)bias)[q];
            o.x = d * fmaxf(d * acc.x + b.x, 0.0f);
            o.y = d * fmaxf(d * acc.y + b.y, 0.0f);
            o.z = d * fmaxf(d * acc.z + b.z, 0.0f);
            o.w = d * fmaxf(d * acc.w + b.w, 0.0f);
        }
        O4[(size_t)i * TPN + q] = o;
    } else {
        O4[(size_t)i * TPN + q] = acc;
    }
}

// ---- mm1: Pd1 = dinv * (x @ W1), K=128 F=16. LDS-tiled.
__global__ __launch_bounds__(256) void k_mm1(const float4* __restrict__ X4,
        const float4* __restrict__ W4, const float* __restrict__ dinv,
        float* __restrict__ out, int n) {
    __shared__ float4 xs[64 * 32];
    __shared__ float4 ws[512];
    int t = threadIdx.x;
    int nb = blockIdx.x * 64;
    ws[t] = W4[t]; ws[t + 256] = W4[t + 256];
    int lim = min(64, n - nb);
    #pragma unroll
    for (int it = 0; it < 8; ++it) {
        int idx = it * 256 + t;
        if ((idx >> 5) < lim) xs[idx] = X4[(size_t)nb * 32 + idx];
    }
    __syncthreads();
    int lane = t & 63, wv = t >> 6;
    int f = lane & 15, kc = lane >> 4;
    float wcol[32];
    #pragma unroll
    for (int kk = 0; kk < 32; ++kk)
        wcol[kk] = ((const float*)ws)[(kc * 32 + kk) * 16 + f];
    for (int ln = wv * 16; ln < wv * 16 + 16; ++ln) {
        if (ln >= lim) break;
        int i = nb + ln;
        float acc = 0.0f;
        #pragma unroll
        for (int j = 0; j < 8; ++j) {
            float4 hv = xs[ln * 32 + kc * 8 + j];
            acc += hv.x * wcol[4 * j]     + hv.y * wcol[4 * j + 1]
                 + hv.z * wcol[4 * j + 2] + hv.w * wcol[4 * j + 3];
        }
        acc += __shfl_xor(acc, 16);
        acc += __shfl_xor(acc, 32);
        if (kc == 0) out[(size_t)i * 16 + f] = acc * dinv[i];
    }
}

// ---- mm2: h2d = dinv * relu(a1 @ W2 + b2), K=16 F=32
__global__ void k_mm2(const float* __restrict__ H, const float* __restrict__ W,
                      const float* __restrict__ b, const float* __restrict__ dinv,
                      float* __restrict__ out, int n, int nwaves) {
    int lane = threadIdx.x & 63;
    int wid = (blockIdx.x * blockDim.x + threadIdx.x) >> 6;
    int f = lane & 31, p = lane >> 5;
    float wcol[16];
    #pragma unroll
    for (int k = 0; k < 16; ++k) wcol[k] = W[k * 32 + f];
    float bias = b[f];
    for (int i0 = wid * 2; i0 < n; i0 += nwaves * 2) {
        int i = i0 + p;
        if (i < n) {
            const float4* h4 = (const float4*)(H + (size_t)i * 16);
            float acc = bias;
            #pragma unroll
            for (int j = 0; j < 4; ++j) {
                float4 hv = h4[j];
                acc += hv.x * wcol[j * 4]     + hv.y * wcol[j * 4 + 1]
                     + hv.z * wcol[j * 4 + 2] + hv.w * wcol[j * 4 + 3];
            }
            out[(size_t)i * 32 + f] = fmaxf(acc, 0.0f) * dinv[i];
        }
    }
}

// ---- mm3: h3 = relu(a2 @ W3 + b3), K=32 F=64
__global__ void k_mm3(const float* __restrict__ H, const float* __restrict__ W,
                      const float* __restrict__ b, float* __restrict__ out,
                      int n, int nwaves) {
    int lane = threadIdx.x & 63;
    int wid = (blockIdx.x * blockDim.x + threadIdx.x) >> 6;
    float wcol[32];
    #pragma unroll
    for (int k = 0; k < 32; ++k) wcol[k] = W[k * 64 + lane];
    float bias = b[lane];
    for (int i = wid; i < n; i += nwaves) {
        const float4* h4 = (const float4*)(H + (size_t)i * 32);
        float acc = bias;
        #pragma unroll
        for (int j = 0; j < 8; ++j) {
            float4 hv = h4[j];
            acc += hv.x * wcol[j * 4]     + hv.y * wcol[j * 4 + 1]
                 + hv.z * wcol[j * 4 + 2] + hv.w * wcol[j * 4 + 3];
        }
        out[(size_t)i * 64 + lane] = fmaxf(acc, 0.0f);
    }
}

// ---- fused mean-pool + MLP head: 256 threads per graph (4-way row parallel)
__global__ __launch_bounds__(256) void k_poolhead(const float* __restrict__ h3,
        const int* __restrict__ batch, const float* __restrict__ Wl1,
        const float* __restrict__ bl1, const float* __restrict__ Wl2,
        const float* __restrict__ bl2, float* __restrict__ out, int n) {
    int g = blockIdx.x, t = threadIdx.x;
    int f = t & 63, r = t >> 6;
    __shared__ int sb[2];
    __shared__ float part[4][64];
    __shared__ float mean[64], hid[64];
    if (t < 2) {
        int target = g + t;
        int lo = 0, hi = n;
        while (lo < hi) {
            int mid = (lo + hi) >> 1;
            if (batch[mid] < target) lo = mid + 1; else hi = mid;
        }
        sb[t] = lo;
    }
    __syncthreads();
    int s = sb[0], e = sb[1];
    float acc = 0.0f;
    for (int i = s + r; i < e; i += 4) acc += h3[(size_t)i * 64 + f];
    part[r][f] = acc;
    __syncthreads();
    if (t < 64) {
        float c = fmaxf((float)(e - s), 1.0f);
        mean[t] = (part[0][t] + part[1][t] + part[2][t] + part[3][t]) / c;
    }
    __syncthreads();
    if (t < 64) {
        float a = bl1[t];
        #pragma unroll 8
        for (int k = 0; k < 64; ++k) a += mean[k] * Wl1[k * 64 + t];
        hid[t] = fmaxf(a, 0.0f);
    }
    __syncthreads();
    if (t < 2) {
        float o = bl2[t];
        #pragma unroll 8
        for (int k = 0; k < 64; ++k) o += hid[k] * Wl2[k * 2 + t];
        out[g * 2 + t] = o;
    }
}

extern "C" void kernel_launch(void* const* d_in, const int* in_sizes, int n_in,
                              void* d_out, int out_size, void* d_ws, size_t ws_size,
                              hipStream_t stream) {
    const float* x    = (const float*)d_in[0];
    const int*   ei   = (const int*)d_in[1];
    const int*   batch= (const int*)d_in[2];
    const float* W1   = (const float*)d_in[3];
    const float* b1   = (const float*)d_in[4];
    const float* W2   = (const float*)d_in[5];
    const float* b2   = (const float*)d_in[6];
    const float* W3   = (const float*)d_in[7];
    const float* b3   = (const float*)d_in[8];
    const float* Wl1  = (const float*)d_in[9];
    const float* bl1  = (const float*)d_in[10];
    const float* Wl2  = (const float*)d_in[11];
    const float* bl2  = (const float*)d_in[12];
    float* out = (float*)d_out;

    const int n  = in_sizes[2];      // 100000
    const int nE = in_sizes[1] / 2;  // 3200000
    const int* src = ei;
    const int* dst = ei + nE;

    const int NSB   = (n + NPSB - 1) / NPSB;   // 196 super-buckets (512 nodes)
    const int NBLK1 = (nE + EPA1 - 1) / EPA1;  // 196 level-1 blocks
    const int NG    = 1024;
    const int qsz   = (n + 3) / 4;             // src-quartile size

    char* w = (char*)d_ws;
    auto alloc_f = [&](size_t cnt) { float* p = (float*)w; w += cnt * 4; return p; };
    auto alloc_i = [&](size_t cnt) { int*   p = (int*)w;   w += cnt * 4; return p; };

    float*    dinv    = alloc_f(n);
    int*      start   = alloc_i(n);
    unsigned* poff    = (unsigned*)alloc_i(n);
    int*      cnt1    = alloc_i((size_t)NBLK1 * PAD1);
    int*      po1     = alloc_i((size_t)NBLK1 * PAD1);
    int*      totals  = alloc_i(256);
    int*      sbstart = alloc_i(256);
    unsigned* ebuf    = (unsigned*)alloc_i(nE);   // 12.8 MB
    int*      col     = alloc_i(nE);              // 12.8 MB (contiguous after ebuf)
    float* Pd1 = alloc_f((size_t)n * 16);
    float* h1d = alloc_f((size_t)n * 16);
    float* a1  = alloc_f((size_t)n * 16);
    float* h2d = alloc_f((size_t)n * 32);
    float* a2  = Pd1;            // 32n over Pd1+h1d (both dead by agg3)
    float* h3  = (float*)ebuf;   // 64n over ebuf+col (dead by mm3)

    const int B = 256;
    auto g = [&](long long t) { return (int)((t + B - 1) / B); };
    const int MMBLK = 1024;
    const int NW = MMBLK * (B / 64);

    // ---- CSR build: two-level radix, zero global atomics
    k_hist1<<<NBLK1, 1024, 0, stream>>>(dst, cnt1, nE, NSB);
    k_scan1<<<NSB, 256, 0, stream>>>(cnt1, po1, totals, NBLK1);
    k_scanB<<<1, 256, 0, stream>>>(totals, sbstart, NSB, nE);
    k_scat1<<<NBLK1, 1024, 0, stream>>>(src, dst, po1, sbstart, ebuf, nE, NSB);
    k_sort2<<<NSB, 512, 0, stream>>>(ebuf, sbstart, col, start, dinv, poff, n, qsz);

    // ---- layer 1: Pd1 = dinv*(x@W1); h1d = dinv*relu(dinv*Agg(Pd1)+b1)
    k_mm1<<<(n + 63) / 64, 256, 0, stream>>>((const float4*)x, (const float4*)W1,
                                             dinv, Pd1, n);
    k_agg<16, 0, 2, 1><<<g((long long)n * 4), B, 0, stream>>>(Pd1, start, poff, col, dinv, b1, h1d, n);
    k_agg<16, 2, 4, 1><<<g((long long)n * 4), B, 0, stream>>>(Pd1, start, poff, col, dinv, b1, h1d, n);

    // ---- layer 2: a1 = dinv*Agg(h1d); h2d = dinv*relu(a1@W2+b2)
    k_agg<16, 0, 2, 0><<<g((long long)n * 4), B, 0, stream>>>(h1d, start, poff, col, dinv, nullptr, a1, n);
    k_agg<16, 2, 4, 0><<<g((long long)n * 4), B, 0, stream>>>(h1d, start, poff, col, dinv, nullptr, a1, n);
    k_mm2<<<MMBLK, B, 0, stream>>>(a1, W2, b2, dinv, h2d, n, NW);

    // ---- layer 3: a2 = dinv*Agg(h2d); h3 = relu(a2@W3+b3)
    k_agg<32, 0, 1, 0><<<g((long long)n * 8), B, 0, stream>>>(h2d, start, poff, col, dinv, nullptr, a2, n);
    k_agg<32, 1, 2, 0><<<g((long long)n * 8), B, 0, stream>>>(h2d, start, poff, col, dinv, nullptr, a2, n);
    k_agg<32, 2, 3, 0><<<g((long long)n * 8), B, 0, stream>>>(h2d, start, poff, col, dinv, nullptr, a2, n);
    k_agg<32, 3, 4, 0><<<g((long long)n * 8), B, 0, stream>>>(h2d, start, poff, col, dinv, nullptr, a2, n);
    k_mm3<<<MMBLK, B, 0, stream>>>(a2, W3, b3, h3, n, NW);

    // ---- fused mean-pool + head (no atomics; batch is sorted)
    k_poolhead<<<NG, 256, 0, stream>>>(h3, batch, Wl1, bl1, Wl2, bl2, out, n);
}

// Round 11
// 257.361 us; speedup vs baseline: 3.0182x; 1.1278x over previous
//
#include <hip/hip_runtime.h>

// GCN forward: 3x GCNConv (symmetric norm, self-loops) + mean-pool + MLP head.
// R11: fused-quartile agg (register accumulator, 8 dispatches -> 3; kills the
//      per-pass out re-read/re-write), scanB folded into scat1/sort2 as an
//      LDS prefix over the tiny totals array. 21 -> 11 dispatches.

constexpr int EPA1 = 16384;  // edges per level-1 block
constexpr int NPSB = 512;    // nodes per super-bucket
constexpr int PAD1 = 200;    // [blk][sb] metadata row stride

// ---- level 1 histogram: per-block super-bucket counts
__global__ __launch_bounds__(1024) void k_hist1(const int* __restrict__ dst,
        int* __restrict__ cnt1, int nE, int NSB) {
    __shared__ int hist[256];
    int t = threadIdx.x;
    if (t < 256) hist[t] = 0;
    __syncthreads();
    int base = blockIdx.x * EPA1, end = min(base + EPA1, nE);
    for (int e = base + t; e < end; e += 1024)
        atomicAdd(&hist[dst[e] >> 9], 1);  // LDS
    __syncthreads();
    if (t < NSB) cnt1[blockIdx.x * PAD1 + t] = hist[t];
}

// ---- level 1 scan: per-sb exclusive prefix over blocks; emits totals
__global__ __launch_bounds__(256) void k_scan1(const int* __restrict__ cnt1,
        int* __restrict__ po1, int* __restrict__ totals, int NBLK1) {
    __shared__ int sc[256];
    int sb = blockIdx.x, t = threadIdx.x;
    int v = (t < NBLK1) ? cnt1[t * PAD1 + sb] : 0;
    sc[t] = v;
    __syncthreads();
    for (int off = 1; off < 256; off <<= 1) {
        int u = (t >= off) ? sc[t - off] : 0;
        __syncthreads();
        sc[t] += u;
        __syncthreads();
    }
    if (t < NBLK1) po1[t * PAD1 + sb] = sc[t] - v;
    if (t == 255) totals[sb] = sc[255];
}

// ---- level 1 scatter: edges -> super-bucket-major ebuf (packed lnode|src).
//      Super-bucket bases derived in-block from totals (LDS scan).
__global__ __launch_bounds__(1024) void k_scat1(const int* __restrict__ src,
        const int* __restrict__ dst, const int* __restrict__ po1,
        const int* __restrict__ totals, unsigned* __restrict__ ebuf,
        int nE, int NSB) {
    __shared__ int sc[256], cur[256];
    int t = threadIdx.x, blk = blockIdx.x;
    if (t < 256) sc[t] = (t < NSB) ? totals[t] : 0;
    __syncthreads();
    for (int off = 1; off < 256; off <<= 1) {
        int u = (t >= off && t < 256) ? sc[t - off] : 0;
        __syncthreads();
        if (t < 256) sc[t] += u;
        __syncthreads();
    }
    if (t < NSB) cur[t] = (sc[t] - totals[t]) + po1[blk * PAD1 + t];
    __syncthreads();
    int base = blk * EPA1, end = min(base + EPA1, nE);
    for (int e = base + t; e < end; e += 1024) {
        int s = src[e], d = dst[e];
        int pos = atomicAdd(&cur[d >> 9], 1);  // LDS
        ebuf[pos] = ((unsigned)(d & 511) << 17) | (unsigned)s;  // ~334B segments
    }
}

// ---- level 2: per-sb contiguous counting sort by (node, src-quartile)
__global__ __launch_bounds__(512) void k_sort2(const unsigned* __restrict__ ebuf,
        const int* __restrict__ totals, int* __restrict__ col,
        int* __restrict__ start, float* __restrict__ dinv,
        unsigned* __restrict__ poff, int n, int qsz, int NSB) {
    __shared__ int sc[256];
    __shared__ int hist4[2048], cur4[2048], excl[512];
    int b = blockIdx.x, t = threadIdx.x;
    if (t < 256) sc[t] = (t < NSB) ? totals[t] : 0;
    __syncthreads();
    for (int off = 1; off < 256; off <<= 1) {
        int u = (t >= off && t < 256) ? sc[t - off] : 0;
        __syncthreads();
        if (t < 256) sc[t] += u;
        __syncthreads();
    }
    int eend = sc[b], ebase = eend - totals[b];
    hist4[t] = 0; hist4[t + 512] = 0; hist4[t + 1024] = 0; hist4[t + 1536] = 0;
    __syncthreads();
    for (int e = ebase + t; e < eend; e += 512) {
        unsigned u = ebuf[e];  // contiguous stream
        atomicAdd(&hist4[(u >> 17) * 4 + (int)(u & 0x1FFFFu) / qsz], 1);  // LDS
    }
    __syncthreads();
    int c0 = hist4[t * 4],     c1 = hist4[t * 4 + 1];
    int c2 = hist4[t * 4 + 2], c3 = hist4[t * 4 + 3];
    int v = c0 + c1 + c2 + c3;
    excl[t] = v;
    __syncthreads();
    for (int off = 1; off < 512; off <<= 1) {
        int u = (t >= off) ? excl[t - off] : 0;
        __syncthreads();
        excl[t] += u;
        __syncthreads();
    }
    int sbase = ebase + excl[t] - v;
    cur4[t * 4]     = sbase;
    cur4[t * 4 + 1] = sbase + c0;
    cur4[t * 4 + 2] = sbase + c0 + c1;
    cur4[t * 4 + 3] = sbase + c0 + c1 + c2;
    int node = (b << 9) + t;
    if (node < n) {
        start[node] = sbase;
        dinv[node] = rsqrtf((float)(v + 1));
        poff[node] = (unsigned)c0 | ((unsigned)c1 << 8) |
                     ((unsigned)c2 << 16) | ((unsigned)c3 << 24);
    }
    __syncthreads();
    for (int e = ebase + t; e < eend; e += 512) {
        unsigned u = ebuf[e];  // L2-hot (read in pass 1)
        int s = (int)(u & 0x1FFFFu);
        int pos = atomicAdd(&cur4[(u >> 17) * 4 + s / qsz], 1);  // LDS
        col[pos] = s;  // ~65KB window
    }
}

// ---- fused aggregation: loop all 4 src-quartiles with register accumulator.
//   EPI 0: out = dinv[i]*total ; EPI 1: out = dinv[i]*relu(dinv[i]*total + b)
template <int F, int EPI>
__global__ void k_aggf(const float* __restrict__ T, const int* __restrict__ start,
                       const unsigned* __restrict__ poff, const int* __restrict__ col,
                       const float* __restrict__ dinv, const float* __restrict__ bias,
                       float* __restrict__ out, int n) {
    constexpr int TPN = F / 4;
    int idx = blockIdx.x * blockDim.x + threadIdx.x;
    int i = idx / TPN;
    int q = idx % TPN;
    if (i >= n) return;
    unsigned pk = poff[i];
    int base = start[i];
    const float4* T4 = (const float4*)T;
    float4 acc = T4[(size_t)i * TPN + q];  // self term
    #pragma unroll
    for (int p = 0; p < 4; ++p) {
        int len = (int)((pk >> (8 * p)) & 255u);
        int k = 0;
        for (; k + 4 <= len; k += 4) {
            int s0 = col[base + k],     s1 = col[base + k + 1];
            int s2 = col[base + k + 2], s3 = col[base + k + 3];
            float4 v0 = T4[(size_t)s0 * TPN + q];
            float4 v1 = T4[(size_t)s1 * TPN + q];
            float4 v2 = T4[(size_t)s2 * TPN + q];
            float4 v3 = T4[(size_t)s3 * TPN + q];
            acc.x += v0.x + v1.x + v2.x + v3.x;
            acc.y += v0.y + v1.y + v2.y + v3.y;
            acc.z += v0.z + v1.z + v2.z + v3.z;
            acc.w += v0.w + v1.w + v2.w + v3.w;
        }
        for (; k < len; ++k) {
            float4 v = T4[(size_t)col[base + k] * TPN + q];
            acc.x += v.x; acc.y += v.y; acc.z += v.z; acc.w += v.w;
        }
        base += len;
    }
    float d = dinv[i];
    float4 o;
    if (EPI == 0) {
        o.x = d * acc.x; o.y = d * acc.y; o.z = d * acc.z; o.w = d * acc.w;
    } else {
        float4 b = ((const float4*)bias)[q];
        o.x = d * fmaxf(d * acc.x + b.x, 0.0f);
        o.y = d * fmaxf(d * acc.y + b.y, 0.0f);
        o.z = d * fmaxf(d * acc.z + b.z, 0.0f);
        o.w = d * fmaxf(d * acc.w + b.w, 0.0f);
    }
    ((float4*)out)[(size_t)i * TPN + q] = o;
}

// ---- mm1: Pd1 = dinv * (x @ W1), K=128 F=16. LDS-tiled.
__global__ __launch_bounds__(256) void k_mm1(const float4* __restrict__ X4,
        const float4* __restrict__ W4, const float* __restrict__ dinv,
        float* __restrict__ out, int n) {
    __shared__ float4 xs[64 * 32];
    __shared__ float4 ws[512];
    int t = threadIdx.x;
    int nb = blockIdx.x * 64;
    ws[t] = W4[t]; ws[t + 256] = W4[t + 256];
    int lim = min(64, n - nb);
    #pragma unroll
    for (int it = 0; it < 8; ++it) {
        int idx = it * 256 + t;
        if ((idx >> 5) < lim) xs[idx] = X4[(size_t)nb * 32 + idx];
    }
    __syncthreads();
    int lane = t & 63, wv = t >> 6;
    int f = lane & 15, kc = lane >> 4;
    float wcol[32];
    #pragma unroll
    for (int kk = 0; kk < 32; ++kk)
        wcol[kk] = ((const float*)ws)[(kc * 32 + kk) * 16 + f];
    for (int ln = wv * 16; ln < wv * 16 + 16; ++ln) {
        if (ln >= lim) break;
        int i = nb + ln;
        float acc = 0.0f;
        #pragma unroll
        for (int j = 0; j < 8; ++j) {
            float4 hv = xs[ln * 32 + kc * 8 + j];
            acc += hv.x * wcol[4 * j]     + hv.y * wcol[4 * j + 1]
                 + hv.z * wcol[4 * j + 2] + hv.w * wcol[4 * j + 3];
        }
        acc += __shfl_xor(acc, 16);
        acc += __shfl_xor(acc, 32);
        if (kc == 0) out[(size_t)i * 16 + f] = acc * dinv[i];
    }
}

// ---- mm2: h2d = dinv * relu(a1 @ W2 + b2), K=16 F=32
__global__ void k_mm2(const float* __restrict__ H, const float* __restrict__ W,
                      const float* __restrict__ b, const float* __restrict__ dinv,
                      float* __restrict__ out, int n, int nwaves) {
    int lane = threadIdx.x & 63;
    int wid = (blockIdx.x * blockDim.x + threadIdx.x) >> 6;
    int f = lane & 31, p = lane >> 5;
    float wcol[16];
    #pragma unroll
    for (int k = 0; k < 16; ++k) wcol[k] = W[k * 32 + f];
    float bias = b[f];
    for (int i0 = wid * 2; i0 < n; i0 += nwaves * 2) {
        int i = i0 + p;
        if (i < n) {
            const float4* h4 = (const float4*)(H + (size_t)i * 16);
            float acc = bias;
            #pragma unroll
            for (int j = 0; j < 4; ++j) {
                float4 hv = h4[j];
                acc += hv.x * wcol[j * 4]     + hv.y * wcol[j * 4 + 1]
                     + hv.z * wcol[j * 4 + 2] + hv.w * wcol[j * 4 + 3];
            }
            out[(size_t)i * 32 + f] = fmaxf(acc, 0.0f) * dinv[i];
        }
    }
}

// ---- mm3: h3 = relu(a2 @ W3 + b3), K=32 F=64
__global__ void k_mm3(const float* __restrict__ H, const float* __restrict__ W,
                      const float* __restrict__ b, float* __restrict__ out,
                      int n, int nwaves) {
    int lane = threadIdx.x & 63;
    int wid = (blockIdx.x * blockDim.x + threadIdx.x) >> 6;
    float wcol[32];
    #pragma unroll
    for (int k = 0; k < 32; ++k) wcol[k] = W[k * 64 + lane];
    float bias = b[lane];
    for (int i = wid; i < n; i += nwaves) {
        const float4* h4 = (const float4*)(H + (size_t)i * 32);
        float acc = bias;
        #pragma unroll
        for (int j = 0; j < 8; ++j) {
            float4 hv = h4[j];
            acc += hv.x * wcol[j * 4]     + hv.y * wcol[j * 4 + 1]
                 + hv.z * wcol[j * 4 + 2] + hv.w * wcol[j * 4 + 3];
        }
        out[(size_t)i * 64 + lane] = fmaxf(acc, 0.0f);
    }
}

// ---- fused mean-pool + MLP head: 256 threads per graph (4-way row parallel)
__global__ __launch_bounds__(256) void k_poolhead(const float* __restrict__ h3,
        const int* __restrict__ batch, const float* __restrict__ Wl1,
        const float* __restrict__ bl1, const float* __restrict__ Wl2,
        const float* __restrict__ bl2, float* __restrict__ out, int n) {
    int g = blockIdx.x, t = threadIdx.x;
    int f = t & 63, r = t >> 6;
    __shared__ int sb[2];
    __shared__ float part[4][64];
    __shared__ float mean[64], hid[64];
    if (t < 2) {
        int target = g + t;
        int lo = 0, hi = n;
        while (lo < hi) {
            int mid = (lo + hi) >> 1;
            if (batch[mid] < target) lo = mid + 1; else hi = mid;
        }
        sb[t] = lo;
    }
    __syncthreads();
    int s = sb[0], e = sb[1];
    float acc = 0.0f;
    for (int i = s + r; i < e; i += 4) acc += h3[(size_t)i * 64 + f];
    part[r][f] = acc;
    __syncthreads();
    if (t < 64) {
        float c = fmaxf((float)(e - s), 1.0f);
        mean[t] = (part[0][t] + part[1][t] + part[2][t] + part[3][t]) / c;
    }
    __syncthreads();
    if (t < 64) {
        float a = bl1[t];
        #pragma unroll 8
        for (int k = 0; k < 64; ++k) a += mean[k] * Wl1[k * 64 + t];
        hid[t] = fmaxf(a, 0.0f);
    }
    __syncthreads();
    if (t < 2) {
        float o = bl2[t];
        #pragma unroll 8
        for (int k = 0; k < 64; ++k) o += hid[k] * Wl2[k * 2 + t];
        out[g * 2 + t] = o;
    }
}

extern "C" void kernel_launch(void* const* d_in, const int* in_sizes, int n_in,
                              void* d_out, int out_size, void* d_ws, size_t ws_size,
                              hipStream_t stream) {
    const float* x    = (const float*)d_in[0];
    const int*   ei   = (const int*)d_in[1];
    const int*   batch= (const int*)d_in[2];
    const float* W1   = (const float*)d_in[3];
    const float* b1   = (const float*)d_in[4];
    const float* W2   = (const float*)d_in[5];
    const float* b2   = (const float*)d_in[6];
    const float* W3   = (const float*)d_in[7];
    const float* b3   = (const float*)d_in[8];
    const float* Wl1  = (const float*)d_in[9];
    const float* bl1  = (const float*)d_in[10];
    const float* Wl2  = (const float*)d_in[11];
    const float* bl2  = (const float*)d_in[12];
    float* out = (float*)d_out;

    const int n  = in_sizes[2];      // 100000
    const int nE = in_sizes[1] / 2;  // 3200000
    const int* src = ei;
    const int* dst = ei + nE;

    const int NSB   = (n + NPSB - 1) / NPSB;   // 196 super-buckets (512 nodes)
    const int NBLK1 = (nE + EPA1 - 1) / EPA1;  // 196 level-1 blocks
    const int NG    = 1024;
    const int qsz   = (n + 3) / 4;             // src-quartile size

    char* w = (char*)d_ws;
    auto alloc_f = [&](size_t cnt) { float* p = (float*)w; w += cnt * 4; return p; };
    auto alloc_i = [&](size_t cnt) { int*   p = (int*)w;   w += cnt * 4; return p; };

    float*    dinv   = alloc_f(n);
    int*      start  = alloc_i(n);
    unsigned* poff   = (unsigned*)alloc_i(n);
    int*      cnt1   = alloc_i((size_t)NBLK1 * PAD1);
    int*      po1    = alloc_i((size_t)NBLK1 * PAD1);
    int*      totals = alloc_i(256);
    unsigned* ebuf   = (unsigned*)alloc_i(nE);   // 12.8 MB
    int*      col    = alloc_i(nE);              // 12.8 MB (contiguous after ebuf)
    float* Pd1 = alloc_f((size_t)n * 16);
    float* h1d = alloc_f((size_t)n * 16);
    float* a1  = alloc_f((size_t)n * 16);
    float* h2d = alloc_f((size_t)n * 32);
    float* a2  = Pd1;            // 32n over Pd1+h1d (both dead by agg3)
    float* h3  = (float*)ebuf;   // 64n over ebuf+col (dead by mm3)

    const int B = 256;
    auto g = [&](long long t) { return (int)((t + B - 1) / B); };
    const int MMBLK = 1024;
    const int NW = MMBLK * (B / 64);

    // ---- CSR build: two-level radix, zero global atomics (11 dispatches total)
    k_hist1<<<NBLK1, 1024, 0, stream>>>(dst, cnt1, nE, NSB);
    k_scan1<<<NSB, 256, 0, stream>>>(cnt1, po1, totals, NBLK1);
    k_scat1<<<NBLK1, 1024, 0, stream>>>(src, dst, po1, totals, ebuf, nE, NSB);
    k_sort2<<<NSB, 512, 0, stream>>>(ebuf, totals, col, start, dinv, poff, n, qsz, NSB);

    // ---- layer 1: Pd1 = dinv*(x@W1); h1d = dinv*relu(dinv*Agg(Pd1)+b1)
    k_mm1<<<(n + 63) / 64, 256, 0, stream>>>((const float4*)x, (const float4*)W1,
                                             dinv, Pd1, n);
    k_aggf<16, 1><<<g((long long)n * 4), B, 0, stream>>>(Pd1, start, poff, col, dinv, b1, h1d, n);

    // ---- layer 2: a1 = dinv*Agg(h1d); h2d = dinv*relu(a1@W2+b2)
    k_aggf<16, 0><<<g((long long)n * 4), B, 0, stream>>>(h1d, start, poff, col, dinv, nullptr, a1, n);
    k_mm2<<<MMBLK, B, 0, stream>>>(a1, W2, b2, dinv, h2d, n, NW);

    // ---- layer 3: a2 = dinv*Agg(h2d); h3 = relu(a2@W3+b3)
    k_aggf<32, 0><<<g((long long)n * 8), B, 0, stream>>>(h2d, start, poff, col, dinv, nullptr, a2, n);
    k_mm3<<<MMBLK, B, 0, stream>>>(a2, W3, b3, h3, n, NW);

    // ---- fused mean-pool + head (no atomics; batch is sorted)
    k_poolhead<<<NG, 256, 0, stream>>>(h3, batch, Wl1, bl1, Wl2, bl2, out, n);
}